// Round 1
// baseline (126.585 us; speedup 1.0000x reference)
//
#include <hip/hip_runtime.h>
#include <math.h>

#define B_ 8
#define N_ 4
#define D_ 256
#define HW_ 3072
#define A_ 256
#define NP_ 3              // view pairs (0,v), v=1..3
#define NJT2_ 48           // 3072 / 64-j partial granularity
#define NJB_ 48            // HW/64 = k_prep blocks per bn (vcnt partials)
#define INV_T 14.2857142857142857f  // 1/0.07
// k_gemm LDS tiles: 64 halves/row (128 B), XOR-swizzled at 16 B granules:
// LDS slot (row, g) holds global granule (g ^ (row & 7)) — an involution, so
// the same XOR is applied on the (pre-swizzled) global source address for
// global_load_lds staging and on the ds_read_b128 fragment reads.
#define LDKH 64

typedef _Float16 half8 __attribute__((ext_vector_type(8)));
typedef _Float16 half2v __attribute__((ext_vector_type(2)));
typedef float f32x4 __attribute__((ext_vector_type(4)));

// ---------------------------------------------------------------------------
// K1 (fused): transpose fp32 [D][HW] -> NORMALIZED fp16 [HW][D], per-column
// fp32 norm computed in-block; view-0 columns additionally scaled by 1/T.
// NEW: the former k_nn (exact-semantics NN search) is fused onto the tail of
// this kernel — it only needs pts (validity recomputed inline), so it has no
// dependency on this kernel's own outputs, and its VALU work hides under the
// block's memory stalls. Grid count matches exactly (1536 blocks).
__global__ __launch_bounds__(256) void k_prep(const float* __restrict__ f,
        const float* __restrict__ pts, _Float16* __restrict__ fh,
        unsigned char* __restrict__ valid, int* __restrict__ vcnt_part,
        const int* __restrict__ aidx, int* __restrict__ pos_idx,
        unsigned char* __restrict__ valid_a, int* __restrict__ ticket) {
  __shared__ unsigned tile[4][64 * 32];
  __shared__ float ssql[4][16][4];
  __shared__ float srn[64];
  int j0 = blockIdx.x * 64;
  int bn = blockIdx.y;
  int n = bn & 3;            // bn = b*N + n
  int tid = threadIdx.x;
  int jq = tid & 15;         // j-quad: j_local = 4*jq + {0..3}
  int dr = tid >> 4;         // 0..15: d-row group: d_local = 4*dr + {0..3}

  if (blockIdx.x == 0 && bn == 0 && tid == 0) *ticket = 0;

  float ssq0 = 0.f, ssq1 = 0.f, ssq2 = 0.f, ssq3 = 0.f;
#pragma unroll
  for (int dt = 0; dt < 4; ++dt) {
    const float* fb = f + ((size_t)bn * D_ + dt * 64 + 4 * dr) * HW_ + j0 + 4 * jq;
    f32x4 r0 = *(const f32x4*)&fb[0];
    f32x4 r1 = *(const f32x4*)&fb[HW_];
    f32x4 r2 = *(const f32x4*)&fb[2 * HW_];
    f32x4 r3 = *(const f32x4*)&fb[3 * HW_];
    ssq0 = fmaf(r0[0], r0[0], fmaf(r1[0], r1[0], fmaf(r2[0], r2[0], fmaf(r3[0], r3[0], ssq0))));
    ssq1 = fmaf(r0[1], r0[1], fmaf(r1[1], r1[1], fmaf(r2[1], r2[1], fmaf(r3[1], r3[1], ssq1))));
    ssq2 = fmaf(r0[2], r0[2], fmaf(r1[2], r1[2], fmaf(r2[2], r2[2], fmaf(r3[2], r3[2], ssq2))));
    ssq3 = fmaf(r0[3], r0[3], fmaf(r1[3], r1[3], fmaf(r2[3], r2[3], fmaf(r3[3], r3[3], ssq3))));
    int p0 = 2 * dr;         // d-pair column within [0,32)
#pragma unroll
    for (int jj = 0; jj < 4; ++jj) {
      int jl = 4 * jq + jj;
      half2v h01, h23;
      h01[0] = (_Float16)r0[jj]; h01[1] = (_Float16)r1[jj];
      h23[0] = (_Float16)r2[jj]; h23[1] = (_Float16)r3[jj];
      tile[dt][jl * 32 + (p0 ^ (jl & 31))]       = __builtin_bit_cast(unsigned, h01);
      tile[dt][jl * 32 + ((p0 + 1) ^ (jl & 31))] = __builtin_bit_cast(unsigned, h23);
    }
  }
  // reduce sumsq over dr within wave (lanes jq, jq+16, jq+32, jq+48)
  ssq0 += __shfl_xor(ssq0, 16); ssq0 += __shfl_xor(ssq0, 32);
  ssq1 += __shfl_xor(ssq1, 16); ssq1 += __shfl_xor(ssq1, 32);
  ssq2 += __shfl_xor(ssq2, 16); ssq2 += __shfl_xor(ssq2, 32);
  ssq3 += __shfl_xor(ssq3, 16); ssq3 += __shfl_xor(ssq3, 32);
  if ((tid & 63) < 16) {
    int w = tid >> 6;
    ssql[w][jq][0] = ssq0; ssql[w][jq][1] = ssq1;
    ssql[w][jq][2] = ssq2; ssql[w][jq][3] = ssq3;
  }
  __syncthreads();
  if (tid < 64) {
    float s = ssql[0][tid >> 2][tid & 3] + ssql[1][tid >> 2][tid & 3]
            + ssql[2][tid >> 2][tid & 3] + ssql[3][tid >> 2][tid & 3];
    float r = 1.f / fmaxf(sqrtf(s), 1e-12f);
    srn[tid] = (n == 0) ? r * INV_T : r;
    size_t idx = (size_t)bn * HW_ + j0 + tid;
    const float* p = pts + idx * 3;
    float x = p[0], y = p[1], z = p[2];
    int v = (x * x + y * y + z * z) > 1e-12f ? 1 : 0;   // ||p|| > 1e-6
    valid[idx] = (unsigned char)v;
    unsigned long long mask = __ballot(v);
    if (tid == 0) vcnt_part[bn * NJB_ + blockIdx.x] = __popcll(mask);
  }
  __syncthreads();
  // readout: scale by srn[j], store 128 B contiguous per 32-lane group
  unsigned* outw = (unsigned*)fh;
  int c = tid & 31;
  int jr = tid >> 5;
#pragma unroll
  for (int dt = 0; dt < 4; ++dt) {
#pragma unroll
    for (int pass = 0; pass < 8; ++pass) {
      int j = jr + pass * 8;
      float sc = srn[j];
      unsigned u = tile[dt][j * 32 + (c ^ (j & 31))];
      half2v h = __builtin_bit_cast(half2v, u);
      half2v o;
      o[0] = (_Float16)((float)h[0] * sc);
      o[1] = (_Float16)((float)h[1] * sc);
      outw[((size_t)bn * HW_ + j0 + j) * (D_ / 2) + dt * 32 + c] =
          __builtin_bit_cast(unsigned, o);
    }
  }

  // ---- fused NN search (exact ref semantics, validity computed inline) ----
  {
    int gid = bn * (HW_ / 64) + blockIdx.x;   // 0..1535, any bijection works
    int wave = tid >> 6, lane = tid & 63;
    int agrp = gid & 63;
    int b = (gid >> 6) & 7;
    int p = gid >> 9;
    int a = agrp * 4 + wave;
    int vv = p + 1;
    int col = aidx[(p * B_ + b) * A_ + a];
    const float* pi = pts + ((size_t)(b * N_) * HW_ + col) * 3;
    float ax = pi[0], ay = pi[1], az = pi[2];
    int vi = (ax * ax + ay * ay + az * az) > 1e-12f ? 1 : 0;
    const float* pj = pts + ((size_t)(b * N_ + vv) * HW_) * 3;
    float best = INFINITY; int bidx = 0x7fffffff;
    for (int j = lane; j < HW_; j += 64) {
      float x = pj[j * 3 + 0], y = pj[j * 3 + 1], z = pj[j * 3 + 2];
      int vj = (x * x + y * y + z * z) > 1e-12f;
      float dx = ax - x, dy = ay - y, dz = az - z;
      float dist = sqrtf(dx * dx + dy * dy + dz * dz);
      if (vj && (dist < best || (dist == best && j < bidx))) { best = dist; bidx = j; }
    }
#pragma unroll
    for (int o = 32; o > 0; o >>= 1) {
      float ob = __shfl_xor(best, o);
      int oi = __shfl_xor(bidx, o);
      if (ob < best || (ob == best && oi < bidx)) { best = ob; bidx = oi; }
    }
    if (lane == 0) {
      int ai = (p * B_ + b) * A_ + a;
      pos_idx[ai] = (bidx == 0x7fffffff) ? 0 : bidx;
      valid_a[ai] = (best < 0.1f) && vi;
    }
  }
}

// ---------------------------------------------------------------------------
// K3: MFMA f16 GEMM, 256 anchors x 128 j per block, BK=64, 8 waves (4x2 of
// 64x64). Inputs pre-normalized (A side pre-scaled by 1/T) -> sim = raw acc.
// NEW STRUCTURE: double-buffered LDS + global_load_lds width=16 staging with
// pre-swizzled global source (linear LDS dest), depth-1 prefetch: K-step kk+1
// is issued before compute of kk, so the single barrier drain per K-step is
// covered by ~32 MFMAs + ds_reads. Barriers: 8 -> 4 per block. s_setprio
// around each 16-MFMA cluster (T5).
// LDS 96 KB -> 1 block/CU, 8 waves = 2 waves/SIMD (HK-template-like regime).
#define STAGE_AB(KK, BUF) do {                                                 \
  _Pragma("unroll")                                                            \
  for (int cc = 0; cc < 4; ++cc) {                                             \
    const _Float16* srcA = fA + (size_t)colA[cc] * D_ + (KK) * 64 + gsw * 8;   \
    __builtin_amdgcn_global_load_lds(                                          \
        (const __attribute__((address_space(1))) void*)srcA,                   \
        (__attribute__((address_space(3))) void*)&As[BUF][(wid * 32 + cc * 8) * LDKH], \
        16, 0, 0);                                                             \
  }                                                                            \
  _Pragma("unroll")                                                            \
  for (int cc = 0; cc < 2; ++cc) {                                             \
    const _Float16* srcB = fB + (size_t)rowB[cc] * D_ + (KK) * 64 + gsw * 8;   \
    __builtin_amdgcn_global_load_lds(                                          \
        (const __attribute__((address_space(1))) void*)srcB,                   \
        (__attribute__((address_space(3))) void*)&Bs[BUF][(wid * 16 + cc * 8) * LDKH], \
        16, 0, 0);                                                             \
  }                                                                            \
} while (0)

__global__ __launch_bounds__(512) void k_gemm(const _Float16* __restrict__ fh,
    const int* __restrict__ aidx, const unsigned char* __restrict__ valid,
    const int* __restrict__ pos_idx, float* __restrict__ possim,
    float2* __restrict__ partials) {
  __shared__ __align__(16) _Float16 As[2][256 * LDKH];   // 2 x 32 KB
  __shared__ __align__(16) _Float16 Bs[2][128 * LDKH];   // 2 x 16 KB
  int jt = blockIdx.x, pb = blockIdx.y;
  int b = pb & 7, p = pb >> 3, v = p + 1;
  int tid = threadIdx.x;
  int wid = tid >> 6, lane = tid & 63;
  int wr = wid >> 1, wc = wid & 1;
  int j0 = jt * 128;
  const _Float16* fA = fh + (size_t)(b * N_) * HW_ * D_;        // view 0
  const _Float16* fB = fh + (size_t)(b * N_ + v) * HW_ * D_;    // view v

  // global_load_lds staging: each wave writes 1024 B linear per call
  // (8 rows x 128 B). lane -> (row = base + (lane>>3), granule slot lane&7).
  // Source granule is pre-swizzled: gsw = (lane&7) ^ (lane>>3) = g ^ (row&7).
  int rl = lane >> 3;
  int gl = lane & 7;
  int gsw = gl ^ rl;
  // A: wave wid covers rows [wid*32, wid*32+32), 4 calls. Rows are gathered
  // anchor columns; each 8-lane group still covers one contiguous 128 B row.
  int colA[4];
#pragma unroll
  for (int c = 0; c < 4; ++c)
    colA[c] = aidx[(p * B_ + b) * A_ + wid * 32 + c * 8 + rl];
  // B: wave wid covers rows [wid*16, wid*16+16), 2 calls.
  int rowB[2];
#pragma unroll
  for (int c = 0; c < 2; ++c) rowB[c] = j0 + wid * 16 + c * 8 + rl;

  f32x4 acc[4][4];
#pragma unroll
  for (int m = 0; m < 4; ++m)
#pragma unroll
    for (int n = 0; n < 4; ++n) acc[m][n] = (f32x4)0.f;

  int kg = lane >> 4;        // k-granule 0..3
  int fr = lane & 15;        // fragment row

  STAGE_AB(0, 0);
  __syncthreads();           // drains vmcnt(0): buf0 ready

#pragma unroll
  for (int kk = 0; kk < 4; ++kk) {
    const int cur = kk & 1;
    if (kk < 3) STAGE_AB(kk + 1, cur ^ 1);   // issue-early: hides under MFMA
#pragma unroll
    for (int s = 0; s < 2; ++s) {
      half8 af[4], bf[4];
      int G = s * 4 + kg;
#pragma unroll
      for (int m = 0; m < 4; ++m) {
        int row = wr * 64 + m * 16 + fr;
        af[m] = *(half8*)&As[cur][row * LDKH + ((G ^ (row & 7)) << 3)];
      }
#pragma unroll
      for (int n = 0; n < 4; ++n) {
        int row = wc * 64 + n * 16 + fr;
        bf[n] = *(half8*)&Bs[cur][row * LDKH + ((G ^ (row & 7)) << 3)];
      }
      __builtin_amdgcn_s_setprio(1);
#pragma unroll
      for (int m = 0; m < 4; ++m)
#pragma unroll
        for (int n = 0; n < 4; ++n)
          acc[m][n] = __builtin_amdgcn_mfma_f32_16x16x32_f16(af[m], bf[n], acc[m][n], 0, 0, 0);
      __builtin_amdgcn_s_setprio(0);
    }
    if (kk < 3) __syncthreads();   // drains prefetch vmcnt; next buf ready
  }

  // ---- epilogue ----
  int jb = j0 + wc * 64;
  int vrow = b * N_ + v;
  int vm[4]; int jn[4];
#pragma unroll
  for (int n = 0; n < 4; ++n) {
    jn[n] = jb + n * 16 + fr;
    vm[n] = valid[(size_t)vrow * HW_ + jn[n]];
  }
#pragma unroll
  for (int m = 0; m < 4; ++m) {
    int abase = wr * 64 + m * 16 + kg * 4;
#pragma unroll
    for (int reg = 0; reg < 4; ++reg) {
      int a = abase + reg;
      int ai = pb * A_ + a;
      int pidx = pos_idx[ai];
      float sv[4]; float mx = -INFINITY;
#pragma unroll
      for (int n = 0; n < 4; ++n) {
        sv[n] = acc[m][n][reg];
        if (vm[n]) mx = fmaxf(mx, sv[n]);
      }
#pragma unroll
      for (int n = 0; n < 4; ++n)
        if (jn[n] == pidx) possim[ai] = sv[n];
#pragma unroll
      for (int o = 1; o < 16; o <<= 1) mx = fmaxf(mx, __shfl_xor(mx, o));
      float S = 0.f;
#pragma unroll
      for (int n = 0; n < 4; ++n)
        if (vm[n]) S += __expf(sv[n] - mx);
#pragma unroll
      for (int o = 1; o < 16; o <<= 1) S += __shfl_xor(S, o);
      if (fr == 0) partials[(size_t)ai * NJT2_ + (jt * 2 + wc)] = make_float2(mx, S);
    }
  }
}

// ---------------------------------------------------------------------------
// K4: merge partial LSEs (4 threads/anchor), per-(pair,batch) reduction +
// include; last block (device ticket) computes the final scalar.
__global__ __launch_bounds__(1024) void k_merge(const float2* __restrict__ partials,
    const float* __restrict__ possim, const unsigned char* __restrict__ valid_a,
    const int* __restrict__ vcnt_part, float* __restrict__ lossb,
    int* __restrict__ incb, int* __restrict__ ticket, float* __restrict__ out) {
  int pb = blockIdx.x;
  int b = pb & 7, p = pb >> 3;
  int tid = threadIdx.x;
  int a = tid >> 2, q = tid & 3;
  int ai = pb * A_ + a;

  __shared__ float ss[16]; __shared__ int sc[16];
  __shared__ int v0c, vvc;
  if (tid == 0) { v0c = 0; vvc = 0; }
  __syncthreads();
  if (tid < NJB_) atomicAdd(&v0c, vcnt_part[(b * N_ + 0) * NJB_ + tid]);
  else if (tid < 2 * NJB_) atomicAdd(&vvc, vcnt_part[(b * N_ + p + 1) * NJB_ + (tid - NJB_)]);

  // each thread: 12 (m,S) pairs = 6 float4, contiguous 96 B
  const float4* pt = (const float4*)partials + (size_t)ai * 24 + q * 6;
  float4 vv4[6];
#pragma unroll
  for (int i = 0; i < 6; ++i) vv4[i] = pt[i];
  float mx = -INFINITY;
#pragma unroll
  for (int i = 0; i < 6; ++i) { mx = fmaxf(mx, vv4[i].x); mx = fmaxf(mx, vv4[i].z); }
  float S = 0.f;
  if (mx != -INFINITY) {
#pragma unroll
    for (int i = 0; i < 6; ++i) {
      S += vv4[i].y * __expf(vv4[i].x - mx);
      S += vv4[i].w * __expf(vv4[i].z - mx);
    }
  }
  // merge across the 4 lanes of this anchor
  float am = mx;
#pragma unroll
  for (int o = 1; o < 4; o <<= 1) am = fmaxf(am, __shfl_xor(am, o));
  float Sg = S * ((mx == am) ? 1.f : __expf(mx - am));
#pragma unroll
  for (int o = 1; o < 4; o <<= 1) Sg += __shfl_xor(Sg, o);

  float contrib = 0.f; int cnt = 0;
  if (q == 0) {
    float lse = (am == -INFINITY) ? -INFINITY : am + logf(Sg);
    if (valid_a[ai]) { contrib = lse - possim[ai]; cnt = 1; }
  }
  // wave reduce (leads are lanes with (lane&3)==0)
#pragma unroll
  for (int o = 4; o < 64; o <<= 1) {
    contrib += __shfl_xor(contrib, o);
    cnt += __shfl_xor(cnt, o);
  }
  if ((tid & 63) == 0) { ss[tid >> 6] = contrib; sc[tid >> 6] = cnt; }
  __syncthreads();
  if (tid == 0) {
    float s = 0.f; int c = 0;
#pragma unroll
    for (int i = 0; i < 16; ++i) { s += ss[i]; c += sc[i]; }
    float lb = s / (float)(c > 1 ? c : 1);
    int inc = (c >= 5) && (v0c >= 10) && (vvc >= 10);
    lossb[pb] = lb;
    incb[pb] = inc;
    __threadfence();
    int old = atomicAdd(ticket, 1);
    if (old == NP_ * B_ - 1) {
      __threadfence();
      float total = 0.f;
      for (int pp = 0; pp < NP_; ++pp) {
        float sacc = 0.f; int n = 0;
        for (int bb = 0; bb < B_; ++bb)
          if (incb[pp * B_ + bb]) { sacc += lossb[pp * B_ + bb]; ++n; }
        total += (n > 0) ? sacc / (float)n : 0.f;
      }
      out[0] = total / (float)NP_;
    }
  }
}

// ---------------------------------------------------------------------------
extern "C" void kernel_launch(void* const* d_in, const int* in_sizes, int n_in,
                              void* d_out, int out_size, void* d_ws, size_t ws_size,
                              hipStream_t stream) {
  const float* f   = (const float*)d_in[0];   // [B,N,D,H,W] fp32
  const float* pts = (const float*)d_in[1];   // [B,N,H,W,3] fp32
  const int* aidx  = (const int*)d_in[2];     // [NP,B,A] int32
  float* out = (float*)d_out;

  char* ws = (char*)d_ws;
  _Float16* fh          = (_Float16*)(ws);                    // 32*3072*256*2 = 50,331,648
  unsigned char* valid  = (unsigned char*)(ws + 50331648);    // 98,304
  int* pos_idx          = (int*)(ws + 50429952);              // 24,576
  unsigned char* valid_a= (unsigned char*)(ws + 50454528);    // 6,144
  float* possim         = (float*)(ws + 50460672);            // 24,576
  float* lossb          = (float*)(ws + 50485248);            // 96 (pad to 128)
  int* incb             = (int*)(ws + 50485376);              // 96 (pad to 128)
  float2* partials      = (float2*)(ws + 50485504);           // 6144*48*8 = 2,359,296
  int* vcnt_part        = (int*)(ws + 52844800);              // 32*48*4 = 6,144
  int* ticket           = (int*)(ws + 52850944);              // 4
  // total ws usage: 52,850,948 bytes

  k_prep<<<dim3(HW_ / 64, B_ * N_), 256, 0, stream>>>(f, pts, fh, valid, vcnt_part,
                                                      aidx, pos_idx, valid_a, ticket);
  k_gemm<<<dim3(24, NP_ * B_), 512, 0, stream>>>(fh, aidx, valid, pos_idx, possim, partials);
  k_merge<<<NP_ * B_, 1024, 0, stream>>>(partials, possim, valid_a, vcnt_part, lossb, incb, ticket, out);
}

// Round 3
// 108.080 us; speedup vs baseline: 1.1712x; 1.1712x over previous
//
#include <hip/hip_runtime.h>
#include <math.h>

#define B_ 8
#define N_ 4
#define D_ 256
#define HW_ 3072
#define A_ 256
#define NP_ 3              // view pairs (0,v), v=1..3
#define NJT2_ 48           // 3072 / 64-j partial granularity
#define NJB_ 48            // HW/64 = k_prep blocks per bn (vcnt partials)
#define INV_T 14.2857142857142857f  // 1/0.07
// k_gemm LDS tiles: 64 halves/row (128 B), XOR-swizzled at 16 B granules:
// LDS slot (row, g) holds global granule (g ^ (row & 7)) — an involution, so
// the same XOR is applied on the (pre-swizzled) global source address for
// global_load_lds staging and on the ds_read_b128 fragment reads.
#define LDKH 64

typedef _Float16 half8 __attribute__((ext_vector_type(8)));
typedef _Float16 half2v __attribute__((ext_vector_type(2)));
typedef float f32x4 __attribute__((ext_vector_type(4)));

// ---------------------------------------------------------------------------
// K1: transpose fp32 [D][HW] -> NORMALIZED fp16 [HW][D], per-column fp32 norm
// computed in-block; view-0 columns additionally scaled by 1/T.
// ROUND-3: reverted byte-for-byte to the round-0/1 known-good body (dword-
// granule XOR swizzle, scalar tile writes/readout). The round-2 quad-swizzle
// restructure is shelved pending the k_nn bisect result.
__global__ __launch_bounds__(256) void k_prep(const float* __restrict__ f,
        const float* __restrict__ pts, _Float16* __restrict__ fh,
        unsigned char* __restrict__ valid, int* __restrict__ vcnt_part) {
  __shared__ unsigned tile[4][64 * 32];
  __shared__ float ssql[4][16][4];
  __shared__ float srn[64];
  int j0 = blockIdx.x * 64;
  int bn = blockIdx.y;
  int n = bn & 3;            // bn = b*N + n
  int tid = threadIdx.x;
  int jq = tid & 15;         // j-quad: j_local = 4*jq + {0..3}
  int dr = tid >> 4;         // 0..15: d-row group: d_local = 4*dr + {0..3}

  float ssq0 = 0.f, ssq1 = 0.f, ssq2 = 0.f, ssq3 = 0.f;
#pragma unroll
  for (int dt = 0; dt < 4; ++dt) {
    const float* fb = f + ((size_t)bn * D_ + dt * 64 + 4 * dr) * HW_ + j0 + 4 * jq;
    f32x4 r0 = *(const f32x4*)&fb[0];
    f32x4 r1 = *(const f32x4*)&fb[HW_];
    f32x4 r2 = *(const f32x4*)&fb[2 * HW_];
    f32x4 r3 = *(const f32x4*)&fb[3 * HW_];
    ssq0 = fmaf(r0[0], r0[0], fmaf(r1[0], r1[0], fmaf(r2[0], r2[0], fmaf(r3[0], r3[0], ssq0))));
    ssq1 = fmaf(r0[1], r0[1], fmaf(r1[1], r1[1], fmaf(r2[1], r2[1], fmaf(r3[1], r3[1], ssq1))));
    ssq2 = fmaf(r0[2], r0[2], fmaf(r1[2], r1[2], fmaf(r2[2], r2[2], fmaf(r3[2], r3[2], ssq2))));
    ssq3 = fmaf(r0[3], r0[3], fmaf(r1[3], r1[3], fmaf(r2[3], r2[3], fmaf(r3[3], r3[3], ssq3))));
    int p0 = 2 * dr;         // d-pair column within [0,32)
#pragma unroll
    for (int jj = 0; jj < 4; ++jj) {
      int jl = 4 * jq + jj;
      half2v h01, h23;
      h01[0] = (_Float16)r0[jj]; h01[1] = (_Float16)r1[jj];
      h23[0] = (_Float16)r2[jj]; h23[1] = (_Float16)r3[jj];
      tile[dt][jl * 32 + (p0 ^ (jl & 31))]       = __builtin_bit_cast(unsigned, h01);
      tile[dt][jl * 32 + ((p0 + 1) ^ (jl & 31))] = __builtin_bit_cast(unsigned, h23);
    }
  }
  // reduce sumsq over dr within wave (lanes jq, jq+16, jq+32, jq+48)
  ssq0 += __shfl_xor(ssq0, 16); ssq0 += __shfl_xor(ssq0, 32);
  ssq1 += __shfl_xor(ssq1, 16); ssq1 += __shfl_xor(ssq1, 32);
  ssq2 += __shfl_xor(ssq2, 16); ssq2 += __shfl_xor(ssq2, 32);
  ssq3 += __shfl_xor(ssq3, 16); ssq3 += __shfl_xor(ssq3, 32);
  if ((tid & 63) < 16) {
    int w = tid >> 6;
    ssql[w][jq][0] = ssq0; ssql[w][jq][1] = ssq1;
    ssql[w][jq][2] = ssq2; ssql[w][jq][3] = ssq3;
  }
  __syncthreads();
  if (tid < 64) {
    float s = ssql[0][tid >> 2][tid & 3] + ssql[1][tid >> 2][tid & 3]
            + ssql[2][tid >> 2][tid & 3] + ssql[3][tid >> 2][tid & 3];
    float r = 1.f / fmaxf(sqrtf(s), 1e-12f);
    srn[tid] = (n == 0) ? r * INV_T : r;
    size_t idx = (size_t)bn * HW_ + j0 + tid;
    const float* p = pts + idx * 3;
    float x = p[0], y = p[1], z = p[2];
    int v = (x * x + y * y + z * z) > 1e-12f ? 1 : 0;   // ||p|| > 1e-6
    valid[idx] = (unsigned char)v;
    unsigned long long mask = __ballot(v);
    if (tid == 0) vcnt_part[bn * NJB_ + blockIdx.x] = __popcll(mask);
  }
  __syncthreads();
  // readout: scale by srn[j], store 128 B contiguous per 32-lane group
  unsigned* outw = (unsigned*)fh;
  int c = tid & 31;
  int jr = tid >> 5;
#pragma unroll
  for (int dt = 0; dt < 4; ++dt) {
#pragma unroll
    for (int pass = 0; pass < 8; ++pass) {
      int j = jr + pass * 8;
      float sc = srn[j];
      unsigned u = tile[dt][j * 32 + (c ^ (j & 31))];
      half2v h = __builtin_bit_cast(half2v, u);
      half2v o;
      o[0] = (_Float16)((float)h[0] * sc);
      o[1] = (_Float16)((float)h[1] * sc);
      outw[((size_t)bn * HW_ + j0 + j) * (D_ / 2) + dt * 32 + c] =
          __builtin_bit_cast(unsigned, o);
    }
  }
}

// ---------------------------------------------------------------------------
// K2: NN search (exact ref semantics), standalone. Vectorized scan: each lane
// covers 4 points/iter via 3x dwordx4 loads (48 B contiguous) -> 12
// iterations instead of 48, 36 VMEM instrs instead of 144. Validity
// recomputed inline (proven by round-1's passing fused version). Full
// within-lane tie-break restored (exact parity with round-0 semantics).
// Also zeroes the merge ticket.
__global__ __launch_bounds__(256) void k_nn(const float* __restrict__ pts,
    const int* __restrict__ aidx, int* __restrict__ pos_idx,
    unsigned char* __restrict__ valid_a, int* __restrict__ ticket) {
  if (blockIdx.x == 0 && threadIdx.x == 0) *ticket = 0;
  int wave = threadIdx.x >> 6, lane = threadIdx.x & 63;
  int gid = blockIdx.x;
  int agrp = gid & 63;
  int b = (gid >> 6) & 7;
  int p = gid >> 9;
  int a = agrp * 4 + wave;
  int vv = p + 1;
  int col = aidx[(p * B_ + b) * A_ + a];
  const float* pi = pts + ((size_t)(b * N_) * HW_ + col) * 3;
  float ax = pi[0], ay = pi[1], az = pi[2];
  int vi = (ax * ax + ay * ay + az * az) > 1e-12f ? 1 : 0;
  const f32x4* pj4 = (const f32x4*)(pts + (size_t)(b * N_ + vv) * HW_ * 3);
  float best = INFINITY; int bidx = 0x7fffffff;
#pragma unroll 2
  for (int t = 0; t < HW_ / 256; ++t) {      // 12 iterations
    int jb = t * 256 + lane * 4;
    int base = t * 192 + lane * 3;           // float4 index: (jb*3)/4
    f32x4 q0 = pj4[base + 0];
    f32x4 q1 = pj4[base + 1];
    f32x4 q2 = pj4[base + 2];
    float px[4] = {q0[0], q0[3], q1[2], q2[1]};
    float py[4] = {q0[1], q1[0], q1[3], q2[2]};
    float pz[4] = {q0[2], q1[1], q2[0], q2[3]};
#pragma unroll
    for (int k = 0; k < 4; ++k) {
      float x = px[k], y = py[k], z = pz[k];
      int vj = (x * x + y * y + z * z) > 1e-12f;
      float dx = ax - x, dy = ay - y, dz = az - z;
      float dist = sqrtf(dx * dx + dy * dy + dz * dz);
      int j = jb + k;
      if (vj && (dist < best || (dist == best && j < bidx))) { best = dist; bidx = j; }
    }
  }
#pragma unroll
  for (int o = 32; o > 0; o >>= 1) {
    float ob = __shfl_xor(best, o);
    int oi = __shfl_xor(bidx, o);
    if (ob < best || (ob == best && oi < bidx)) { best = ob; bidx = oi; }
  }
  if (lane == 0) {
    int ai = (p * B_ + b) * A_ + a;
    pos_idx[ai] = (bidx == 0x7fffffff) ? 0 : bidx;
    valid_a[ai] = (best < 0.1f) && vi;
  }
}

// ---------------------------------------------------------------------------
// K3: MFMA f16 GEMM, 256 anchors x 128 j per block, BK=64, 8 waves (4x2 of
// 64x64). Inputs pre-normalized (A side pre-scaled by 1/T) -> sim = raw acc.
// Double-buffered LDS + global_load_lds width=16 staging with pre-swizzled
// global source (linear LDS dest), depth-1 prefetch: K-step kk+1 is issued
// before compute of kk. Barriers: 4 per block. s_setprio around MFMA (T5).
#define STAGE_AB(KK, BUF) do {                                                 \
  _Pragma("unroll")                                                            \
  for (int cc = 0; cc < 4; ++cc) {                                             \
    const _Float16* srcA = fA + (size_t)colA[cc] * D_ + (KK) * 64 + gsw * 8;   \
    __builtin_amdgcn_global_load_lds(                                          \
        (const __attribute__((address_space(1))) void*)srcA,                   \
        (__attribute__((address_space(3))) void*)&As[BUF][(wid * 32 + cc * 8) * LDKH], \
        16, 0, 0);                                                             \
  }                                                                            \
  _Pragma("unroll")                                                            \
  for (int cc = 0; cc < 2; ++cc) {                                             \
    const _Float16* srcB = fB + (size_t)rowB[cc] * D_ + (KK) * 64 + gsw * 8;   \
    __builtin_amdgcn_global_load_lds(                                          \
        (const __attribute__((address_space(1))) void*)srcB,                   \
        (__attribute__((address_space(3))) void*)&Bs[BUF][(wid * 16 + cc * 8) * LDKH], \
        16, 0, 0);                                                             \
  }                                                                            \
} while (0)

__global__ __launch_bounds__(512) void k_gemm(const _Float16* __restrict__ fh,
    const int* __restrict__ aidx, const unsigned char* __restrict__ valid,
    const int* __restrict__ pos_idx, float* __restrict__ possim,
    float2* __restrict__ partials) {
  __shared__ __align__(16) _Float16 As[2][256 * LDKH];   // 2 x 32 KB
  __shared__ __align__(16) _Float16 Bs[2][128 * LDKH];   // 2 x 16 KB
  int jt = blockIdx.x, pb = blockIdx.y;
  int b = pb & 7, p = pb >> 3, v = p + 1;
  int tid = threadIdx.x;
  int wid = tid >> 6, lane = tid & 63;
  int wr = wid >> 1, wc = wid & 1;
  int j0 = jt * 128;
  const _Float16* fA = fh + (size_t)(b * N_) * HW_ * D_;        // view 0
  const _Float16* fB = fh + (size_t)(b * N_ + v) * HW_ * D_;    // view v

  // global_load_lds staging: each wave writes 1024 B linear per call
  // (8 rows x 128 B). lane -> (row = base + (lane>>3), granule slot lane&7).
  // Source granule is pre-swizzled: gsw = (lane&7) ^ (lane>>3) = g ^ (row&7).
  int rl = lane >> 3;
  int gl = lane & 7;
  int gsw = gl ^ rl;
  int colA[4];
#pragma unroll
  for (int c = 0; c < 4; ++c)
    colA[c] = aidx[(p * B_ + b) * A_ + wid * 32 + c * 8 + rl];
  int rowB[2];
#pragma unroll
  for (int c = 0; c < 2; ++c) rowB[c] = j0 + wid * 16 + c * 8 + rl;

  f32x4 acc[4][4];
#pragma unroll
  for (int m = 0; m < 4; ++m)
#pragma unroll
    for (int n = 0; n < 4; ++n) acc[m][n] = (f32x4)0.f;

  int kg = lane >> 4;        // k-granule 0..3
  int fr = lane & 15;        // fragment row

  STAGE_AB(0, 0);
  __syncthreads();           // drains vmcnt(0): buf0 ready

#pragma unroll
  for (int kk = 0; kk < 4; ++kk) {
    const int cur = kk & 1;
    if (kk < 3) STAGE_AB(kk + 1, cur ^ 1);   // issue-early: hides under MFMA
#pragma unroll
    for (int s = 0; s < 2; ++s) {
      half8 af[4], bf[4];
      int G = s * 4 + kg;
#pragma unroll
      for (int m = 0; m < 4; ++m) {
        int row = wr * 64 + m * 16 + fr;
        af[m] = *(half8*)&As[cur][row * LDKH + ((G ^ (row & 7)) << 3)];
      }
#pragma unroll
      for (int n = 0; n < 4; ++n) {
        int row = wc * 64 + n * 16 + fr;
        bf[n] = *(half8*)&Bs[cur][row * LDKH + ((G ^ (row & 7)) << 3)];
      }
      __builtin_amdgcn_s_setprio(1);
#pragma unroll
      for (int m = 0; m < 4; ++m)
#pragma unroll
        for (int n = 0; n < 4; ++n)
          acc[m][n] = __builtin_amdgcn_mfma_f32_16x16x32_f16(af[m], bf[n], acc[m][n], 0, 0, 0);
      __builtin_amdgcn_s_setprio(0);
    }
    if (kk < 3) __syncthreads();   // drains prefetch vmcnt; next buf ready
  }

  // ---- epilogue ----
  int jb = j0 + wc * 64;
  int vrow = b * N_ + v;
  int vm[4]; int jn[4];
#pragma unroll
  for (int n = 0; n < 4; ++n) {
    jn[n] = jb + n * 16 + fr;
    vm[n] = valid[(size_t)vrow * HW_ + jn[n]];
  }
#pragma unroll
  for (int m = 0; m < 4; ++m) {
    int abase = wr * 64 + m * 16 + kg * 4;
#pragma unroll
    for (int reg = 0; reg < 4; ++reg) {
      int a = abase + reg;
      int ai = pb * A_ + a;
      int pidx = pos_idx[ai];
      float sv[4]; float mx = -INFINITY;
#pragma unroll
      for (int n = 0; n < 4; ++n) {
        sv[n] = acc[m][n][reg];
        if (vm[n]) mx = fmaxf(mx, sv[n]);
      }
#pragma unroll
      for (int n = 0; n < 4; ++n)
        if (jn[n] == pidx) possim[ai] = sv[n];
#pragma unroll
      for (int o = 1; o < 16; o <<= 1) mx = fmaxf(mx, __shfl_xor(mx, o));
      float S = 0.f;
#pragma unroll
      for (int n = 0; n < 4; ++n)
        if (vm[n]) S += __expf(sv[n] - mx);
#pragma unroll
      for (int o = 1; o < 16; o <<= 1) S += __shfl_xor(S, o);
      if (fr == 0) partials[(size_t)ai * NJT2_ + (jt * 2 + wc)] = make_float2(mx, S);
    }
  }
}

// ---------------------------------------------------------------------------
// K4: merge partial LSEs (4 threads/anchor), per-(pair,batch) reduction +
// include; last block (device ticket) computes the final scalar.
__global__ __launch_bounds__(1024) void k_merge(const float2* __restrict__ partials,
    const float* __restrict__ possim, const unsigned char* __restrict__ valid_a,
    const int* __restrict__ vcnt_part, float* __restrict__ lossb,
    int* __restrict__ incb, int* __restrict__ ticket, float* __restrict__ out) {
  int pb = blockIdx.x;
  int b = pb & 7, p = pb >> 3;
  int tid = threadIdx.x;
  int a = tid >> 2, q = tid & 3;
  int ai = pb * A_ + a;

  __shared__ float ss[16]; __shared__ int sc[16];
  __shared__ int v0c, vvc;
  if (tid == 0) { v0c = 0; vvc = 0; }
  __syncthreads();
  if (tid < NJB_) atomicAdd(&v0c, vcnt_part[(b * N_ + 0) * NJB_ + tid]);
  else if (tid < 2 * NJB_) atomicAdd(&vvc, vcnt_part[(b * N_ + p + 1) * NJB_ + (tid - NJB_)]);

  // each thread: 12 (m,S) pairs = 6 float4, contiguous 96 B
  const float4* pt = (const float4*)partials + (size_t)ai * 24 + q * 6;
  float4 vv4[6];
#pragma unroll
  for (int i = 0; i < 6; ++i) vv4[i] = pt[i];
  float mx = -INFINITY;
#pragma unroll
  for (int i = 0; i < 6; ++i) { mx = fmaxf(mx, vv4[i].x); mx = fmaxf(mx, vv4[i].z); }
  float S = 0.f;
  if (mx != -INFINITY) {
#pragma unroll
    for (int i = 0; i < 6; ++i) {
      S += vv4[i].y * __expf(vv4[i].x - mx);
      S += vv4[i].w * __expf(vv4[i].z - mx);
    }
  }
  // merge across the 4 lanes of this anchor
  float am = mx;
#pragma unroll
  for (int o = 1; o < 4; o <<= 1) am = fmaxf(am, __shfl_xor(am, o));
  float Sg = S * ((mx == am) ? 1.f : __expf(mx - am));
#pragma unroll
  for (int o = 1; o < 4; o <<= 1) Sg += __shfl_xor(Sg, o);

  float contrib = 0.f; int cnt = 0;
  if (q == 0) {
    float lse = (am == -INFINITY) ? -INFINITY : am + logf(Sg);
    if (valid_a[ai]) { contrib = lse - possim[ai]; cnt = 1; }
  }
  // wave reduce (leads are lanes with (lane&3)==0)
#pragma unroll
  for (int o = 4; o < 64; o <<= 1) {
    contrib += __shfl_xor(contrib, o);
    cnt += __shfl_xor(cnt, o);
  }
  if ((tid & 63) == 0) { ss[tid >> 6] = contrib; sc[tid >> 6] = cnt; }
  __syncthreads();
  if (tid == 0) {
    float s = 0.f; int c = 0;
#pragma unroll
    for (int i = 0; i < 16; ++i) { s += ss[i]; c += sc[i]; }
    float lb = s / (float)(c > 1 ? c : 1);
    int inc = (c >= 5) && (v0c >= 10) && (vvc >= 10);
    lossb[pb] = lb;
    incb[pb] = inc;
    __threadfence();
    int old = atomicAdd(ticket, 1);
    if (old == NP_ * B_ - 1) {
      __threadfence();
      float total = 0.f;
      for (int pp = 0; pp < NP_; ++pp) {
        float sacc = 0.f; int n = 0;
        for (int bb = 0; bb < B_; ++bb)
          if (incb[pp * B_ + bb]) { sacc += lossb[pp * B_ + bb]; ++n; }
        total += (n > 0) ? sacc / (float)n : 0.f;
      }
      out[0] = total / (float)NP_;
    }
  }
}

// ---------------------------------------------------------------------------
extern "C" void kernel_launch(void* const* d_in, const int* in_sizes, int n_in,
                              void* d_out, int out_size, void* d_ws, size_t ws_size,
                              hipStream_t stream) {
  const float* f   = (const float*)d_in[0];   // [B,N,D,H,W] fp32
  const float* pts = (const float*)d_in[1];   // [B,N,H,W,3] fp32
  const int* aidx  = (const int*)d_in[2];     // [NP,B,A] int32
  float* out = (float*)d_out;

  char* ws = (char*)d_ws;
  _Float16* fh          = (_Float16*)(ws);                    // 32*3072*256*2 = 50,331,648
  unsigned char* valid  = (unsigned char*)(ws + 50331648);    // 98,304
  int* pos_idx          = (int*)(ws + 50429952);              // 24,576
  unsigned char* valid_a= (unsigned char*)(ws + 50454528);    // 6,144
  float* possim         = (float*)(ws + 50460672);            // 24,576
  float* lossb          = (float*)(ws + 50485248);            // 96 (pad to 128)
  int* incb             = (int*)(ws + 50485376);              // 96 (pad to 128)
  float2* partials      = (float2*)(ws + 50485504);           // 6144*48*8 = 2,359,296
  int* vcnt_part        = (int*)(ws + 52844800);              // 32*48*4 = 6,144
  int* ticket           = (int*)(ws + 52850944);              // 4
  // total ws usage: 52,850,948 bytes

  k_prep<<<dim3(HW_ / 64, B_ * N_), 256, 0, stream>>>(f, pts, fh, valid, vcnt_part);
  k_nn<<<NP_ * B_ * (A_ / 4), 256, 0, stream>>>(pts, aidx, pos_idx, valid_a, ticket);
  k_gemm<<<dim3(24, NP_ * B_), 512, 0, stream>>>(fh, aidx, valid, pos_idx, possim, partials);
  k_merge<<<NP_ * B_, 1024, 0, stream>>>(partials, possim, valid_a, vcnt_part, lossb, incb, ticket, out);
}

// Round 4
// 108.058 us; speedup vs baseline: 1.1715x; 1.0002x over previous
//
#include <hip/hip_runtime.h>
#include <math.h>

#define B_ 8
#define N_ 4
#define D_ 256
#define HW_ 3072
#define A_ 256
#define NP_ 3              // view pairs (0,v), v=1..3
#define NJT2_ 48           // 3072 / 64-j partial granularity
#define NJB_ 48            // HW/64 = k_prep blocks per bn (vcnt partials)
#define INV_T 14.2857142857142857f  // 1/0.07
// k_gemm LDS tiles: 64 halves/row (128 B), XOR-swizzled at 16 B granules:
// LDS slot (row, g) holds global granule (g ^ (row & 7)) — an involution, so
// the same XOR is applied on the (pre-swizzled) global source address for
// global_load_lds staging and on the ds_read_b128 fragment reads.
#define LDKH 64

typedef _Float16 half8 __attribute__((ext_vector_type(8)));
typedef _Float16 half2v __attribute__((ext_vector_type(2)));
typedef float f32x4 __attribute__((ext_vector_type(4)));

// ---------------------------------------------------------------------------
// K1: transpose fp32 [D][HW] -> NORMALIZED fp16 [HW][D], per-column fp32 norm
// computed in-block; view-0 columns additionally scaled by 1/T.
// (round-0/1 known-good body, frozen)
__global__ __launch_bounds__(256) void k_prep(const float* __restrict__ f,
        const float* __restrict__ pts, _Float16* __restrict__ fh,
        unsigned char* __restrict__ valid, int* __restrict__ vcnt_part) {
  __shared__ unsigned tile[4][64 * 32];
  __shared__ float ssql[4][16][4];
  __shared__ float srn[64];
  int j0 = blockIdx.x * 64;
  int bn = blockIdx.y;
  int n = bn & 3;            // bn = b*N + n
  int tid = threadIdx.x;
  int jq = tid & 15;         // j-quad: j_local = 4*jq + {0..3}
  int dr = tid >> 4;         // 0..15: d-row group: d_local = 4*dr + {0..3}

  float ssq0 = 0.f, ssq1 = 0.f, ssq2 = 0.f, ssq3 = 0.f;
#pragma unroll
  for (int dt = 0; dt < 4; ++dt) {
    const float* fb = f + ((size_t)bn * D_ + dt * 64 + 4 * dr) * HW_ + j0 + 4 * jq;
    f32x4 r0 = *(const f32x4*)&fb[0];
    f32x4 r1 = *(const f32x4*)&fb[HW_];
    f32x4 r2 = *(const f32x4*)&fb[2 * HW_];
    f32x4 r3 = *(const f32x4*)&fb[3 * HW_];
    ssq0 = fmaf(r0[0], r0[0], fmaf(r1[0], r1[0], fmaf(r2[0], r2[0], fmaf(r3[0], r3[0], ssq0))));
    ssq1 = fmaf(r0[1], r0[1], fmaf(r1[1], r1[1], fmaf(r2[1], r2[1], fmaf(r3[1], r3[1], ssq1))));
    ssq2 = fmaf(r0[2], r0[2], fmaf(r1[2], r1[2], fmaf(r2[2], r2[2], fmaf(r3[2], r3[2], ssq2))));
    ssq3 = fmaf(r0[3], r0[3], fmaf(r1[3], r1[3], fmaf(r2[3], r2[3], fmaf(r3[3], r3[3], ssq3))));
    int p0 = 2 * dr;         // d-pair column within [0,32)
#pragma unroll
    for (int jj = 0; jj < 4; ++jj) {
      int jl = 4 * jq + jj;
      half2v h01, h23;
      h01[0] = (_Float16)r0[jj]; h01[1] = (_Float16)r1[jj];
      h23[0] = (_Float16)r2[jj]; h23[1] = (_Float16)r3[jj];
      tile[dt][jl * 32 + (p0 ^ (jl & 31))]       = __builtin_bit_cast(unsigned, h01);
      tile[dt][jl * 32 + ((p0 + 1) ^ (jl & 31))] = __builtin_bit_cast(unsigned, h23);
    }
  }
  // reduce sumsq over dr within wave (lanes jq, jq+16, jq+32, jq+48)
  ssq0 += __shfl_xor(ssq0, 16); ssq0 += __shfl_xor(ssq0, 32);
  ssq1 += __shfl_xor(ssq1, 16); ssq1 += __shfl_xor(ssq1, 32);
  ssq2 += __shfl_xor(ssq2, 16); ssq2 += __shfl_xor(ssq2, 32);
  ssq3 += __shfl_xor(ssq3, 16); ssq3 += __shfl_xor(ssq3, 32);
  if ((tid & 63) < 16) {
    int w = tid >> 6;
    ssql[w][jq][0] = ssq0; ssql[w][jq][1] = ssq1;
    ssql[w][jq][2] = ssq2; ssql[w][jq][3] = ssq3;
  }
  __syncthreads();
  if (tid < 64) {
    float s = ssql[0][tid >> 2][tid & 3] + ssql[1][tid >> 2][tid & 3]
            + ssql[2][tid >> 2][tid & 3] + ssql[3][tid >> 2][tid & 3];
    float r = 1.f / fmaxf(sqrtf(s), 1e-12f);
    srn[tid] = (n == 0) ? r * INV_T : r;
    size_t idx = (size_t)bn * HW_ + j0 + tid;
    const float* p = pts + idx * 3;
    float x = p[0], y = p[1], z = p[2];
    int v = (x * x + y * y + z * z) > 1e-12f ? 1 : 0;   // ||p|| > 1e-6
    valid[idx] = (unsigned char)v;
    unsigned long long mask = __ballot(v);
    if (tid == 0) vcnt_part[bn * NJB_ + blockIdx.x] = __popcll(mask);
  }
  __syncthreads();
  // readout: scale by srn[j], store 128 B contiguous per 32-lane group
  unsigned* outw = (unsigned*)fh;
  int c = tid & 31;
  int jr = tid >> 5;
#pragma unroll
  for (int dt = 0; dt < 4; ++dt) {
#pragma unroll
    for (int pass = 0; pass < 8; ++pass) {
      int j = jr + pass * 8;
      float sc = srn[j];
      unsigned u = tile[dt][j * 32 + (c ^ (j & 31))];
      half2v h = __builtin_bit_cast(half2v, u);
      half2v o;
      o[0] = (_Float16)((float)h[0] * sc);
      o[1] = (_Float16)((float)h[1] * sc);
      outw[((size_t)bn * HW_ + j0 + j) * (D_ / 2) + dt * 32 + c] =
          __builtin_bit_cast(unsigned, o);
    }
  }
}

// ---------------------------------------------------------------------------
// K2: NN search (exact ref semantics), standalone, vectorized scan (proven
// round 3). Also zeroes the merge ticket.
__global__ __launch_bounds__(256) void k_nn(const float* __restrict__ pts,
    const int* __restrict__ aidx, int* __restrict__ pos_idx,
    unsigned char* __restrict__ valid_a, int* __restrict__ ticket) {
  if (blockIdx.x == 0 && threadIdx.x == 0) *ticket = 0;
  int wave = threadIdx.x >> 6, lane = threadIdx.x & 63;
  int gid = blockIdx.x;
  int agrp = gid & 63;
  int b = (gid >> 6) & 7;
  int p = gid >> 9;
  int a = agrp * 4 + wave;
  int vv = p + 1;
  int col = aidx[(p * B_ + b) * A_ + a];
  const float* pi = pts + ((size_t)(b * N_) * HW_ + col) * 3;
  float ax = pi[0], ay = pi[1], az = pi[2];
  int vi = (ax * ax + ay * ay + az * az) > 1e-12f ? 1 : 0;
  const f32x4* pj4 = (const f32x4*)(pts + (size_t)(b * N_ + vv) * HW_ * 3);
  float best = INFINITY; int bidx = 0x7fffffff;
#pragma unroll 2
  for (int t = 0; t < HW_ / 256; ++t) {      // 12 iterations
    int jb = t * 256 + lane * 4;
    int base = t * 192 + lane * 3;           // float4 index: (jb*3)/4
    f32x4 q0 = pj4[base + 0];
    f32x4 q1 = pj4[base + 1];
    f32x4 q2 = pj4[base + 2];
    float px[4] = {q0[0], q0[3], q1[2], q2[1]};
    float py[4] = {q0[1], q1[0], q1[3], q2[2]};
    float pz[4] = {q0[2], q1[1], q2[0], q2[3]};
#pragma unroll
    for (int k = 0; k < 4; ++k) {
      float x = px[k], y = py[k], z = pz[k];
      int vj = (x * x + y * y + z * z) > 1e-12f;
      float dx = ax - x, dy = ay - y, dz = az - z;
      float dist = sqrtf(dx * dx + dy * dy + dz * dz);
      int j = jb + k;
      if (vj && (dist < best || (dist == best && j < bidx))) { best = dist; bidx = j; }
    }
  }
#pragma unroll
  for (int o = 32; o > 0; o >>= 1) {
    float ob = __shfl_xor(best, o);
    int oi = __shfl_xor(bidx, o);
    if (ob < best || (ob == best && oi < bidx)) { best = ob; bidx = oi; }
  }
  if (lane == 0) {
    int ai = (p * B_ + b) * A_ + a;
    pos_idx[ai] = (bidx == 0x7fffffff) ? 0 : bidx;
    valid_a[ai] = (best < 0.1f) && vi;
  }
}

// ---------------------------------------------------------------------------
// K3: MFMA f16 GEMM, 256 anchors x 128 j per block, BK=64, 8 waves (4x2 of
// 64x64). Inputs pre-normalized (A side pre-scaled by 1/T) -> sim = raw acc.
// ROUND-4: T4 deep pipeline. Triple-buffered LDS (144 KB); ALL K-steps'
// staging is issued as early as possible (kk=0,1,2 in the prologue, kk=3
// right after buf0 is consumed) via global_load_lds width=16 with
// pre-swizzled global source. Sync = raw s_barrier + counted inline-asm
// s_waitcnt vmcnt(N) — never a full drain inside the loop, so up to 18
// loads/wave stay in flight and the memory pipe streams instead of
// burst-and-wait. vmcnt ledger (6 loads/wave per K-step, in-order counting):
//   issued: 18 prologue, +6 after kk=0  -> waits: kk0:12, kk1:12, kk2:6, kk3:0
// Barriers/wave: 4 data-ready + 1 buffer-free = 5, uniform (no divergence).
#define STAGE_AB(KK, BUF) do {                                                 \
  _Pragma("unroll")                                                            \
  for (int cc = 0; cc < 4; ++cc) {                                             \
    const _Float16* srcA = fA + (size_t)colA[cc] * D_ + (KK) * 64 + gsw * 8;   \
    __builtin_amdgcn_global_load_lds(                                          \
        (const __attribute__((address_space(1))) void*)srcA,                   \
        (__attribute__((address_space(3))) void*)&As[BUF][(wid * 32 + cc * 8) * LDKH], \
        16, 0, 0);                                                             \
  }                                                                            \
  _Pragma("unroll")                                                            \
  for (int cc = 0; cc < 2; ++cc) {                                             \
    const _Float16* srcB = fB + (size_t)rowB[cc] * D_ + (KK) * 64 + gsw * 8;   \
    __builtin_amdgcn_global_load_lds(                                          \
        (const __attribute__((address_space(1))) void*)srcB,                   \
        (__attribute__((address_space(3))) void*)&Bs[BUF][(wid * 16 + cc * 8) * LDKH], \
        16, 0, 0);                                                             \
  }                                                                            \
} while (0)

__global__ __launch_bounds__(512) void k_gemm(const _Float16* __restrict__ fh,
    const int* __restrict__ aidx, const unsigned char* __restrict__ valid,
    const int* __restrict__ pos_idx, float* __restrict__ possim,
    float2* __restrict__ partials) {
  __shared__ __align__(16) _Float16 As[3][256 * LDKH];   // 3 x 32 KB
  __shared__ __align__(16) _Float16 Bs[3][128 * LDKH];   // 3 x 16 KB
  int jt = blockIdx.x, pb = blockIdx.y;
  int b = pb & 7, p = pb >> 3, v = p + 1;
  int tid = threadIdx.x;
  int wid = tid >> 6, lane = tid & 63;
  int wr = wid >> 1, wc = wid & 1;
  int j0 = jt * 128;
  const _Float16* fA = fh + (size_t)(b * N_) * HW_ * D_;        // view 0
  const _Float16* fB = fh + (size_t)(b * N_ + v) * HW_ * D_;    // view v

  // global_load_lds staging: each wave writes 1024 B linear per call
  // (8 rows x 128 B). lane -> (row = base + (lane>>3), granule slot lane&7).
  // Source granule is pre-swizzled: gsw = (lane&7) ^ (lane>>3) = g ^ (row&7).
  int rl = lane >> 3;
  int gl = lane & 7;
  int gsw = gl ^ rl;
  int colA[4];
#pragma unroll
  for (int c = 0; c < 4; ++c)
    colA[c] = aidx[(p * B_ + b) * A_ + wid * 32 + c * 8 + rl];
  int rowB[2];
#pragma unroll
  for (int c = 0; c < 2; ++c) rowB[c] = j0 + wid * 16 + c * 8 + rl;

  f32x4 acc[4][4];
#pragma unroll
  for (int m = 0; m < 4; ++m)
#pragma unroll
    for (int n = 0; n < 4; ++n) acc[m][n] = (f32x4)0.f;

  int kg = lane >> 4;        // k-granule 0..3
  int fr = lane & 15;        // fragment row

  // prologue: put 3 K-steps (18 loads/wave, 144 KB/block) in flight
  STAGE_AB(0, 0);
  STAGE_AB(1, 1);
  STAGE_AB(2, 2);

#pragma unroll
  for (int kk = 0; kk < 4; ++kk) {
    const int cur = kk % 3;          // buffers: 0,1,2,0
    // data-ready gate for buf `cur`: own oldest loads complete + barrier
    if (kk <= 1)      asm volatile("s_waitcnt vmcnt(12)" ::: "memory");
    else if (kk == 2) asm volatile("s_waitcnt vmcnt(6)"  ::: "memory");
    else              asm volatile("s_waitcnt vmcnt(0)"  ::: "memory");
    __builtin_amdgcn_s_barrier();
    __builtin_amdgcn_sched_barrier(0);
#pragma unroll
    for (int s = 0; s < 2; ++s) {
      half8 af[4], bf[4];
      int G = s * 4 + kg;
#pragma unroll
      for (int m = 0; m < 4; ++m) {
        int row = wr * 64 + m * 16 + fr;
        af[m] = *(half8*)&As[cur][row * LDKH + ((G ^ (row & 7)) << 3)];
      }
#pragma unroll
      for (int n = 0; n < 4; ++n) {
        int row = wc * 64 + n * 16 + fr;
        bf[n] = *(half8*)&Bs[cur][row * LDKH + ((G ^ (row & 7)) << 3)];
      }
      __builtin_amdgcn_s_setprio(1);
#pragma unroll
      for (int m = 0; m < 4; ++m)
#pragma unroll
        for (int n = 0; n < 4; ++n)
          acc[m][n] = __builtin_amdgcn_mfma_f32_16x16x32_f16(af[m], bf[n], acc[m][n], 0, 0, 0);
      __builtin_amdgcn_s_setprio(0);
    }
    if (kk == 0) {
      // buffer-free gate: all waves consumed buf0 (ds_reads retired by MFMA
      // consumption) -> safe to overwrite with kk=3's data
      __builtin_amdgcn_s_barrier();
      __builtin_amdgcn_sched_barrier(0);
      STAGE_AB(3, 0);
    }
  }

  // ---- epilogue ----
  int jb = j0 + wc * 64;
  int vrow = b * N_ + v;
  int vm[4]; int jn[4];
#pragma unroll
  for (int n = 0; n < 4; ++n) {
    jn[n] = jb + n * 16 + fr;
    vm[n] = valid[(size_t)vrow * HW_ + jn[n]];
  }
#pragma unroll
  for (int m = 0; m < 4; ++m) {
    int abase = wr * 64 + m * 16 + kg * 4;
#pragma unroll
    for (int reg = 0; reg < 4; ++reg) {
      int a = abase + reg;
      int ai = pb * A_ + a;
      int pidx = pos_idx[ai];
      float sv[4]; float mx = -INFINITY;
#pragma unroll
      for (int n = 0; n < 4; ++n) {
        sv[n] = acc[m][n][reg];
        if (vm[n]) mx = fmaxf(mx, sv[n]);
      }
#pragma unroll
      for (int n = 0; n < 4; ++n)
        if (jn[n] == pidx) possim[ai] = sv[n];
#pragma unroll
      for (int o = 1; o < 16; o <<= 1) mx = fmaxf(mx, __shfl_xor(mx, o));
      float S = 0.f;
#pragma unroll
      for (int n = 0; n < 4; ++n)
        if (vm[n]) S += __expf(sv[n] - mx);
#pragma unroll
      for (int o = 1; o < 16; o <<= 1) S += __shfl_xor(S, o);
      if (fr == 0) partials[(size_t)ai * NJT2_ + (jt * 2 + wc)] = make_float2(mx, S);
    }
  }
}

// ---------------------------------------------------------------------------
// K4: merge partial LSEs (4 threads/anchor), per-(pair,batch) reduction +
// include; last block (device ticket) computes the final scalar.
__global__ __launch_bounds__(1024) void k_merge(const float2* __restrict__ partials,
    const float* __restrict__ possim, const unsigned char* __restrict__ valid_a,
    const int* __restrict__ vcnt_part, float* __restrict__ lossb,
    int* __restrict__ incb, int* __restrict__ ticket, float* __restrict__ out) {
  int pb = blockIdx.x;
  int b = pb & 7, p = pb >> 3;
  int tid = threadIdx.x;
  int a = tid >> 2, q = tid & 3;
  int ai = pb * A_ + a;

  __shared__ float ss[16]; __shared__ int sc[16];
  __shared__ int v0c, vvc;
  if (tid == 0) { v0c = 0; vvc = 0; }
  __syncthreads();
  if (tid < NJB_) atomicAdd(&v0c, vcnt_part[(b * N_ + 0) * NJB_ + tid]);
  else if (tid < 2 * NJB_) atomicAdd(&vvc, vcnt_part[(b * N_ + p + 1) * NJB_ + (tid - NJB_)]);

  // each thread: 12 (m,S) pairs = 6 float4, contiguous 96 B
  const float4* pt = (const float4*)partials + (size_t)ai * 24 + q * 6;
  float4 vv4[6];
#pragma unroll
  for (int i = 0; i < 6; ++i) vv4[i] = pt[i];
  float mx = -INFINITY;
#pragma unroll
  for (int i = 0; i < 6; ++i) { mx = fmaxf(mx, vv4[i].x); mx = fmaxf(mx, vv4[i].z); }
  float S = 0.f;
  if (mx != -INFINITY) {
#pragma unroll
    for (int i = 0; i < 6; ++i) {
      S += vv4[i].y * __expf(vv4[i].x - mx);
      S += vv4[i].w * __expf(vv4[i].z - mx);
    }
  }
  // merge across the 4 lanes of this anchor
  float am = mx;
#pragma unroll
  for (int o = 1; o < 4; o <<= 1) am = fmaxf(am, __shfl_xor(am, o));
  float Sg = S * ((mx == am) ? 1.f : __expf(mx - am));
#pragma unroll
  for (int o = 1; o < 4; o <<= 1) Sg += __shfl_xor(Sg, o);

  float contrib = 0.f; int cnt = 0;
  if (q == 0) {
    float lse = (am == -INFINITY) ? -INFINITY : am + logf(Sg);
    if (valid_a[ai]) { contrib = lse - possim[ai]; cnt = 1; }
  }
  // wave reduce (leads are lanes with (lane&3)==0)
#pragma unroll
  for (int o = 4; o < 64; o <<= 1) {
    contrib += __shfl_xor(contrib, o);
    cnt += __shfl_xor(cnt, o);
  }
  if ((tid & 63) == 0) { ss[tid >> 6] = contrib; sc[tid >> 6] = cnt; }
  __syncthreads();
  if (tid == 0) {
    float s = 0.f; int c = 0;
#pragma unroll
    for (int i = 0; i < 16; ++i) { s += ss[i]; c += sc[i]; }
    float lb = s / (float)(c > 1 ? c : 1);
    int inc = (c >= 5) && (v0c >= 10) && (vvc >= 10);
    lossb[pb] = lb;
    incb[pb] = inc;
    __threadfence();
    int old = atomicAdd(ticket, 1);
    if (old == NP_ * B_ - 1) {
      __threadfence();
      float total = 0.f;
      for (int pp = 0; pp < NP_; ++pp) {
        float sacc = 0.f; int n = 0;
        for (int bb = 0; bb < B_; ++bb)
          if (incb[pp * B_ + bb]) { sacc += lossb[pp * B_ + bb]; ++n; }
        total += (n > 0) ? sacc / (float)n : 0.f;
      }
      out[0] = total / (float)NP_;
    }
  }
}

// ---------------------------------------------------------------------------
extern "C" void kernel_launch(void* const* d_in, const int* in_sizes, int n_in,
                              void* d_out, int out_size, void* d_ws, size_t ws_size,
                              hipStream_t stream) {
  const float* f   = (const float*)d_in[0];   // [B,N,D,H,W] fp32
  const float* pts = (const float*)d_in[1];   // [B,N,H,W,3] fp32
  const int* aidx  = (const int*)d_in[2];     // [NP,B,A] int32
  float* out = (float*)d_out;

  char* ws = (char*)d_ws;
  _Float16* fh          = (_Float16*)(ws);                    // 32*3072*256*2 = 50,331,648
  unsigned char* valid  = (unsigned char*)(ws + 50331648);    // 98,304
  int* pos_idx          = (int*)(ws + 50429952);              // 24,576
  unsigned char* valid_a= (unsigned char*)(ws + 50454528);    // 6,144
  float* possim         = (float*)(ws + 50460672);            // 24,576
  float* lossb          = (float*)(ws + 50485248);            // 96 (pad to 128)
  int* incb             = (int*)(ws + 50485376);              // 96 (pad to 128)
  float2* partials      = (float2*)(ws + 50485504);           // 6144*48*8 = 2,359,296
  int* vcnt_part        = (int*)(ws + 52844800);              // 32*48*4 = 6,144
  int* ticket           = (int*)(ws + 52850944);              // 4
  // total ws usage: 52,850,948 bytes

  k_prep<<<dim3(HW_ / 64, B_ * N_), 256, 0, stream>>>(f, pts, fh, valid, vcnt_part);
  k_nn<<<NP_ * B_ * (A_ / 4), 256, 0, stream>>>(pts, aidx, pos_idx, valid_a, ticket);
  k_gemm<<<dim3(24, NP_ * B_), 512, 0, stream>>>(fh, aidx, valid, pos_idx, possim, partials);
  k_merge<<<NP_ * B_, 1024, 0, stream>>>(partials, possim, valid_a, vcnt_part, lossb, incb, ticket, out);
}

// Round 5
// 104.482 us; speedup vs baseline: 1.2115x; 1.0342x over previous
//
#include <hip/hip_runtime.h>
#include <math.h>

#define B_ 8
#define N_ 4
#define D_ 256
#define HW_ 3072
#define A_ 256
#define NP_ 3              // view pairs (0,v), v=1..3
#define NJT2_ 48           // 3072 / 64-j partial granularity
#define NJB_ 48            // HW/64 = k_prep blocks per bn (vcnt partials)
#define INV_T 14.2857142857142857f  // 1/0.07
// k_gemm LDS tiles: 64 halves/row (128 B), XOR-swizzled at 16 B granules:
// LDS slot (row, g) holds global granule (g ^ (row & 7)) — an involution, so
// the same XOR is applied on the (pre-swizzled) global source address for
// global_load_lds staging and on the ds_read_b128 fragment reads.
#define LDKH 64

typedef _Float16 half8 __attribute__((ext_vector_type(8)));
typedef _Float16 half2v __attribute__((ext_vector_type(2)));
typedef float f32x4 __attribute__((ext_vector_type(4)));

// ---------------------------------------------------------------------------
// K1: transpose fp32 [D][HW] -> NORMALIZED fp16 [HW][D], per-column fp32 norm
// computed in-block; view-0 columns additionally scaled by 1/T.
// (round-0/1 known-good body, frozen)
__global__ __launch_bounds__(256) void k_prep(const float* __restrict__ f,
        const float* __restrict__ pts, _Float16* __restrict__ fh,
        unsigned char* __restrict__ valid, int* __restrict__ vcnt_part) {
  __shared__ unsigned tile[4][64 * 32];
  __shared__ float ssql[4][16][4];
  __shared__ float srn[64];
  int j0 = blockIdx.x * 64;
  int bn = blockIdx.y;
  int n = bn & 3;            // bn = b*N + n
  int tid = threadIdx.x;
  int jq = tid & 15;         // j-quad: j_local = 4*jq + {0..3}
  int dr = tid >> 4;         // 0..15: d-row group: d_local = 4*dr + {0..3}

  float ssq0 = 0.f, ssq1 = 0.f, ssq2 = 0.f, ssq3 = 0.f;
#pragma unroll
  for (int dt = 0; dt < 4; ++dt) {
    const float* fb = f + ((size_t)bn * D_ + dt * 64 + 4 * dr) * HW_ + j0 + 4 * jq;
    f32x4 r0 = *(const f32x4*)&fb[0];
    f32x4 r1 = *(const f32x4*)&fb[HW_];
    f32x4 r2 = *(const f32x4*)&fb[2 * HW_];
    f32x4 r3 = *(const f32x4*)&fb[3 * HW_];
    ssq0 = fmaf(r0[0], r0[0], fmaf(r1[0], r1[0], fmaf(r2[0], r2[0], fmaf(r3[0], r3[0], ssq0))));
    ssq1 = fmaf(r0[1], r0[1], fmaf(r1[1], r1[1], fmaf(r2[1], r2[1], fmaf(r3[1], r3[1], ssq1))));
    ssq2 = fmaf(r0[2], r0[2], fmaf(r1[2], r1[2], fmaf(r2[2], r2[2], fmaf(r3[2], r3[2], ssq2))));
    ssq3 = fmaf(r0[3], r0[3], fmaf(r1[3], r1[3], fmaf(r2[3], r2[3], fmaf(r3[3], r3[3], ssq3))));
    int p0 = 2 * dr;         // d-pair column within [0,32)
#pragma unroll
    for (int jj = 0; jj < 4; ++jj) {
      int jl = 4 * jq + jj;
      half2v h01, h23;
      h01[0] = (_Float16)r0[jj]; h01[1] = (_Float16)r1[jj];
      h23[0] = (_Float16)r2[jj]; h23[1] = (_Float16)r3[jj];
      tile[dt][jl * 32 + (p0 ^ (jl & 31))]       = __builtin_bit_cast(unsigned, h01);
      tile[dt][jl * 32 + ((p0 + 1) ^ (jl & 31))] = __builtin_bit_cast(unsigned, h23);
    }
  }
  // reduce sumsq over dr within wave (lanes jq, jq+16, jq+32, jq+48)
  ssq0 += __shfl_xor(ssq0, 16); ssq0 += __shfl_xor(ssq0, 32);
  ssq1 += __shfl_xor(ssq1, 16); ssq1 += __shfl_xor(ssq1, 32);
  ssq2 += __shfl_xor(ssq2, 16); ssq2 += __shfl_xor(ssq2, 32);
  ssq3 += __shfl_xor(ssq3, 16); ssq3 += __shfl_xor(ssq3, 32);
  if ((tid & 63) < 16) {
    int w = tid >> 6;
    ssql[w][jq][0] = ssq0; ssql[w][jq][1] = ssq1;
    ssql[w][jq][2] = ssq2; ssql[w][jq][3] = ssq3;
  }
  __syncthreads();
  if (tid < 64) {
    float s = ssql[0][tid >> 2][tid & 3] + ssql[1][tid >> 2][tid & 3]
            + ssql[2][tid >> 2][tid & 3] + ssql[3][tid >> 2][tid & 3];
    float r = 1.f / fmaxf(sqrtf(s), 1e-12f);
    srn[tid] = (n == 0) ? r * INV_T : r;
    size_t idx = (size_t)bn * HW_ + j0 + tid;
    const float* p = pts + idx * 3;
    float x = p[0], y = p[1], z = p[2];
    int v = (x * x + y * y + z * z) > 1e-12f ? 1 : 0;   // ||p|| > 1e-6
    valid[idx] = (unsigned char)v;
    unsigned long long mask = __ballot(v);
    if (tid == 0) vcnt_part[bn * NJB_ + blockIdx.x] = __popcll(mask);
  }
  __syncthreads();
  // readout: scale by srn[j], store 128 B contiguous per 32-lane group
  unsigned* outw = (unsigned*)fh;
  int c = tid & 31;
  int jr = tid >> 5;
#pragma unroll
  for (int dt = 0; dt < 4; ++dt) {
#pragma unroll
    for (int pass = 0; pass < 8; ++pass) {
      int j = jr + pass * 8;
      float sc = srn[j];
      unsigned u = tile[dt][j * 32 + (c ^ (j & 31))];
      half2v h = __builtin_bit_cast(half2v, u);
      half2v o;
      o[0] = (_Float16)((float)h[0] * sc);
      o[1] = (_Float16)((float)h[1] * sc);
      outw[((size_t)bn * HW_ + j0 + j) * (D_ / 2) + dt * 32 + c] =
          __builtin_bit_cast(unsigned, o);
    }
  }
}

// ---------------------------------------------------------------------------
// K2: NN search (exact ref semantics), standalone, vectorized scan (proven
// round 3). Also zeroes the merge ticket.
__global__ __launch_bounds__(256) void k_nn(const float* __restrict__ pts,
    const int* __restrict__ aidx, int* __restrict__ pos_idx,
    unsigned char* __restrict__ valid_a, int* __restrict__ ticket) {
  if (blockIdx.x == 0 && threadIdx.x == 0) *ticket = 0;
  int wave = threadIdx.x >> 6, lane = threadIdx.x & 63;
  int gid = blockIdx.x;
  int agrp = gid & 63;
  int b = (gid >> 6) & 7;
  int p = gid >> 9;
  int a = agrp * 4 + wave;
  int vv = p + 1;
  int col = aidx[(p * B_ + b) * A_ + a];
  const float* pi = pts + ((size_t)(b * N_) * HW_ + col) * 3;
  float ax = pi[0], ay = pi[1], az = pi[2];
  int vi = (ax * ax + ay * ay + az * az) > 1e-12f ? 1 : 0;
  const f32x4* pj4 = (const f32x4*)(pts + (size_t)(b * N_ + vv) * HW_ * 3);
  float best = INFINITY; int bidx = 0x7fffffff;
#pragma unroll 2
  for (int t = 0; t < HW_ / 256; ++t) {      // 12 iterations
    int jb = t * 256 + lane * 4;
    int base = t * 192 + lane * 3;           // float4 index: (jb*3)/4
    f32x4 q0 = pj4[base + 0];
    f32x4 q1 = pj4[base + 1];
    f32x4 q2 = pj4[base + 2];
    float px[4] = {q0[0], q0[3], q1[2], q2[1]};
    float py[4] = {q0[1], q1[0], q1[3], q2[2]};
    float pz[4] = {q0[2], q1[1], q2[0], q2[3]};
#pragma unroll
    for (int k = 0; k < 4; ++k) {
      float x = px[k], y = py[k], z = pz[k];
      int vj = (x * x + y * y + z * z) > 1e-12f;
      float dx = ax - x, dy = ay - y, dz = az - z;
      float dist = sqrtf(dx * dx + dy * dy + dz * dz);
      int j = jb + k;
      if (vj && (dist < best || (dist == best && j < bidx))) { best = dist; bidx = j; }
    }
  }
#pragma unroll
  for (int o = 32; o > 0; o >>= 1) {
    float ob = __shfl_xor(best, o);
    int oi = __shfl_xor(bidx, o);
    if (ob < best || (ob == best && oi < bidx)) { best = ob; bidx = oi; }
  }
  if (lane == 0) {
    int ai = (p * B_ + b) * A_ + a;
    pos_idx[ai] = (bidx == 0x7fffffff) ? 0 : bidx;
    valid_a[ai] = (best < 0.1f) && vi;
  }
}

// ---------------------------------------------------------------------------
// K3: MFMA f16 GEMM. ROUND-5 DISCRIMINATOR: tile 256x128 -> 128x128, 4 waves
// (2x2 of 64x64), LDS 64 KB -> 2 blocks/CU, grid 576 -> 1152 blocks.
// Schedule is round-3's proven __syncthreads double-buffer (round-4's counted
// vmcnt bought exactly nothing). Per-wave fragment/epilogue code unchanged.
// Hypotheses: H1 (1-block/CU stall exposure) predicts ~2x faster; H2
// (gathered global_load_lds throughput limit) predicts ~33% SLOWER (bytes
// staged 110 -> 147 MB). Either outcome attributes the 60 us.
#define STAGE_AB(KK, BUF) do {                                                 \
  _Pragma("unroll")                                                            \
  for (int cc = 0; cc < 4; ++cc) {                                             \
    const _Float16* srcA = fA + (size_t)colA[cc] * D_ + (KK) * 64 + gsw * 8;   \
    __builtin_amdgcn_global_load_lds(                                          \
        (const __attribute__((address_space(1))) void*)srcA,                   \
        (__attribute__((address_space(3))) void*)&As[BUF][(wid * 32 + cc * 8) * LDKH], \
        16, 0, 0);                                                             \
  }                                                                            \
  _Pragma("unroll")                                                            \
  for (int cc = 0; cc < 4; ++cc) {                                             \
    const _Float16* srcB = fB + (size_t)rowB[cc] * D_ + (KK) * 64 + gsw * 8;   \
    __builtin_amdgcn_global_load_lds(                                          \
        (const __attribute__((address_space(1))) void*)srcB,                   \
        (__attribute__((address_space(3))) void*)&Bs[BUF][(wid * 32 + cc * 8) * LDKH], \
        16, 0, 0);                                                             \
  }                                                                            \
} while (0)

__global__ __launch_bounds__(256) void k_gemm(const _Float16* __restrict__ fh,
    const int* __restrict__ aidx, const unsigned char* __restrict__ valid,
    const int* __restrict__ pos_idx, float* __restrict__ possim,
    float2* __restrict__ partials) {
  __shared__ __align__(16) _Float16 As[2][128 * LDKH];   // 2 x 16 KB
  __shared__ __align__(16) _Float16 Bs[2][128 * LDKH];   // 2 x 16 KB
  int jt = blockIdx.x;
  int pbm = blockIdx.y;          // 0..47: pb*2 + mt
  int pb = pbm >> 1, mt = pbm & 1;
  int b = pb & 7, p = pb >> 3, v = p + 1;
  int tid = threadIdx.x;
  int wid = tid >> 6, lane = tid & 63;   // 4 waves
  int wr = wid >> 1, wc = wid & 1;       // 2x2 of 64x64
  int j0 = jt * 128;
  const _Float16* fA = fh + (size_t)(b * N_) * HW_ * D_;        // view 0
  const _Float16* fB = fh + (size_t)(b * N_ + v) * HW_ * D_;    // view v

  // staging: each wave covers 32 A-rows and 32 B-rows per K-step (4+4 calls
  // of 8 rows each). lane -> (row offset rl = lane>>3, granule gl = lane&7),
  // source granule pre-swizzled: gsw = gl ^ rl = g ^ (row&7).
  int rl = lane >> 3;
  int gl = lane & 7;
  int gsw = gl ^ rl;
  int colA[4];
#pragma unroll
  for (int c = 0; c < 4; ++c)
    colA[c] = aidx[(p * B_ + b) * A_ + mt * 128 + wid * 32 + c * 8 + rl];
  int rowB[4];
#pragma unroll
  for (int c = 0; c < 4; ++c) rowB[c] = j0 + wid * 32 + c * 8 + rl;

  f32x4 acc[4][4];
#pragma unroll
  for (int m = 0; m < 4; ++m)
#pragma unroll
    for (int n = 0; n < 4; ++n) acc[m][n] = (f32x4)0.f;

  int kg = lane >> 4;        // k-granule 0..3
  int fr = lane & 15;        // fragment row

  STAGE_AB(0, 0);
  __syncthreads();           // drains vmcnt(0): buf0 ready

#pragma unroll
  for (int kk = 0; kk < 4; ++kk) {
    const int cur = kk & 1;
    if (kk < 3) STAGE_AB(kk + 1, cur ^ 1);   // issue-early: hides under MFMA
#pragma unroll
    for (int s = 0; s < 2; ++s) {
      half8 af[4], bf[4];
      int G = s * 4 + kg;
#pragma unroll
      for (int m = 0; m < 4; ++m) {
        int row = wr * 64 + m * 16 + fr;
        af[m] = *(half8*)&As[cur][row * LDKH + ((G ^ (row & 7)) << 3)];
      }
#pragma unroll
      for (int n = 0; n < 4; ++n) {
        int row = wc * 64 + n * 16 + fr;
        bf[n] = *(half8*)&Bs[cur][row * LDKH + ((G ^ (row & 7)) << 3)];
      }
      __builtin_amdgcn_s_setprio(1);
#pragma unroll
      for (int m = 0; m < 4; ++m)
#pragma unroll
        for (int n = 0; n < 4; ++n)
          acc[m][n] = __builtin_amdgcn_mfma_f32_16x16x32_f16(af[m], bf[n], acc[m][n], 0, 0, 0);
      __builtin_amdgcn_s_setprio(0);
    }
    if (kk < 3) __syncthreads();   // drains prefetch vmcnt; next buf ready
  }

  // ---- epilogue (identical math; anchor base shifted by mt*128) ----
  int jb = j0 + wc * 64;
  int vrow = b * N_ + v;
  int vm[4]; int jn[4];
#pragma unroll
  for (int n = 0; n < 4; ++n) {
    jn[n] = jb + n * 16 + fr;
    vm[n] = valid[(size_t)vrow * HW_ + jn[n]];
  }
#pragma unroll
  for (int m = 0; m < 4; ++m) {
    int abase = mt * 128 + wr * 64 + m * 16 + kg * 4;
#pragma unroll
    for (int reg = 0; reg < 4; ++reg) {
      int a = abase + reg;
      int ai = pb * A_ + a;
      int pidx = pos_idx[ai];
      float sv[4]; float mx = -INFINITY;
#pragma unroll
      for (int n = 0; n < 4; ++n) {
        sv[n] = acc[m][n][reg];
        if (vm[n]) mx = fmaxf(mx, sv[n]);
      }
#pragma unroll
      for (int n = 0; n < 4; ++n)
        if (jn[n] == pidx) possim[ai] = sv[n];
#pragma unroll
      for (int o = 1; o < 16; o <<= 1) mx = fmaxf(mx, __shfl_xor(mx, o));
      float S = 0.f;
#pragma unroll
      for (int n = 0; n < 4; ++n)
        if (vm[n]) S += __expf(sv[n] - mx);
#pragma unroll
      for (int o = 1; o < 16; o <<= 1) S += __shfl_xor(S, o);
      if (fr == 0) partials[(size_t)ai * NJT2_ + (jt * 2 + wc)] = make_float2(mx, S);
    }
  }
}

// ---------------------------------------------------------------------------
// K4: merge partial LSEs (4 threads/anchor), per-(pair,batch) reduction +
// include; last block (device ticket) computes the final scalar.
__global__ __launch_bounds__(1024) void k_merge(const float2* __restrict__ partials,
    const float* __restrict__ possim, const unsigned char* __restrict__ valid_a,
    const int* __restrict__ vcnt_part, float* __restrict__ lossb,
    int* __restrict__ incb, int* __restrict__ ticket, float* __restrict__ out) {
  int pb = blockIdx.x;
  int b = pb & 7, p = pb >> 3;
  int tid = threadIdx.x;
  int a = tid >> 2, q = tid & 3;
  int ai = pb * A_ + a;

  __shared__ float ss[16]; __shared__ int sc[16];
  __shared__ int v0c, vvc;
  if (tid == 0) { v0c = 0; vvc = 0; }
  __syncthreads();
  if (tid < NJB_) atomicAdd(&v0c, vcnt_part[(b * N_ + 0) * NJB_ + tid]);
  else if (tid < 2 * NJB_) atomicAdd(&vvc, vcnt_part[(b * N_ + p + 1) * NJB_ + (tid - NJB_)]);

  // each thread: 12 (m,S) pairs = 6 float4, contiguous 96 B
  const float4* pt = (const float4*)partials + (size_t)ai * 24 + q * 6;
  float4 vv4[6];
#pragma unroll
  for (int i = 0; i < 6; ++i) vv4[i] = pt[i];
  float mx = -INFINITY;
#pragma unroll
  for (int i = 0; i < 6; ++i) { mx = fmaxf(mx, vv4[i].x); mx = fmaxf(mx, vv4[i].z); }
  float S = 0.f;
  if (mx != -INFINITY) {
#pragma unroll
    for (int i = 0; i < 6; ++i) {
      S += vv4[i].y * __expf(vv4[i].x - mx);
      S += vv4[i].w * __expf(vv4[i].z - mx);
    }
  }
  // merge across the 4 lanes of this anchor
  float am = mx;
#pragma unroll
  for (int o = 1; o < 4; o <<= 1) am = fmaxf(am, __shfl_xor(am, o));
  float Sg = S * ((mx == am) ? 1.f : __expf(mx - am));
#pragma unroll
  for (int o = 1; o < 4; o <<= 1) Sg += __shfl_xor(Sg, o);

  float contrib = 0.f; int cnt = 0;
  if (q == 0) {
    float lse = (am == -INFINITY) ? -INFINITY : am + logf(Sg);
    if (valid_a[ai]) { contrib = lse - possim[ai]; cnt = 1; }
  }
  // wave reduce (leads are lanes with (lane&3)==0)
#pragma unroll
  for (int o = 4; o < 64; o <<= 1) {
    contrib += __shfl_xor(contrib, o);
    cnt += __shfl_xor(cnt, o);
  }
  if ((tid & 63) == 0) { ss[tid >> 6] = contrib; sc[tid >> 6] = cnt; }
  __syncthreads();
  if (tid == 0) {
    float s = 0.f; int c = 0;
#pragma unroll
    for (int i = 0; i < 16; ++i) { s += ss[i]; c += sc[i]; }
    float lb = s / (float)(c > 1 ? c : 1);
    int inc = (c >= 5) && (v0c >= 10) && (vvc >= 10);
    lossb[pb] = lb;
    incb[pb] = inc;
    __threadfence();
    int old = atomicAdd(ticket, 1);
    if (old == NP_ * B_ - 1) {
      __threadfence();
      float total = 0.f;
      for (int pp = 0; pp < NP_; ++pp) {
        float sacc = 0.f; int n = 0;
        for (int bb = 0; bb < B_; ++bb)
          if (incb[pp * B_ + bb]) { sacc += lossb[pp * B_ + bb]; ++n; }
        total += (n > 0) ? sacc / (float)n : 0.f;
      }
      out[0] = total / (float)NP_;
    }
  }
}

// ---------------------------------------------------------------------------
extern "C" void kernel_launch(void* const* d_in, const int* in_sizes, int n_in,
                              void* d_out, int out_size, void* d_ws, size_t ws_size,
                              hipStream_t stream) {
  const float* f   = (const float*)d_in[0];   // [B,N,D,H,W] fp32
  const float* pts = (const float*)d_in[1];   // [B,N,H,W,3] fp32
  const int* aidx  = (const int*)d_in[2];     // [NP,B,A] int32
  float* out = (float*)d_out;

  char* ws = (char*)d_ws;
  _Float16* fh          = (_Float16*)(ws);                    // 32*3072*256*2 = 50,331,648
  unsigned char* valid  = (unsigned char*)(ws + 50331648);    // 98,304
  int* pos_idx          = (int*)(ws + 50429952);              // 24,576
  unsigned char* valid_a= (unsigned char*)(ws + 50454528);    // 6,144
  float* possim         = (float*)(ws + 50460672);            // 24,576
  float* lossb          = (float*)(ws + 50485248);            // 96 (pad to 128)
  int* incb             = (int*)(ws + 50485376);              // 96 (pad to 128)
  float2* partials      = (float2*)(ws + 50485504);           // 6144*48*8 = 2,359,296
  int* vcnt_part        = (int*)(ws + 52844800);              // 32*48*4 = 6,144
  int* ticket           = (int*)(ws + 52850944);              // 4
  // total ws usage: 52,850,948 bytes

  k_prep<<<dim3(HW_ / 64, B_ * N_), 256, 0, stream>>>(f, pts, fh, valid, vcnt_part);
  k_nn<<<NP_ * B_ * (A_ / 4), 256, 0, stream>>>(pts, aidx, pos_idx, valid_a, ticket);
  k_gemm<<<dim3(24, NP_ * B_ * 2), 256, 0, stream>>>(fh, aidx, valid, pos_idx, possim, partials);
  k_merge<<<NP_ * B_, 1024, 0, stream>>>(partials, possim, valid_a, vcnt_part, lossb, incb, ticket, out);
}

// Round 6
// 90.303 us; speedup vs baseline: 1.4018x; 1.1570x over previous
//
#include <hip/hip_runtime.h>
#include <math.h>

#define B_ 8
#define N_ 4
#define D_ 256
#define HW_ 3072
#define A_ 256
#define NP_ 3              // view pairs (0,v), v=1..3
#define NJT2_ 48           // 3072 / 64-j partial granularity
#define NJB_ 48            // HW/64 = k_prep blocks per bn (vcnt partials)
#define INV_T 14.2857142857142857f  // 1/0.07
#define LDKH 64

typedef _Float16 half8 __attribute__((ext_vector_type(8)));
typedef _Float16 half2v __attribute__((ext_vector_type(2)));
typedef float f32x4 __attribute__((ext_vector_type(4)));

// ---------------------------------------------------------------------------
// K1: transpose fp32 [D][HW] -> NORMALIZED fp16 [HW][D], per-column fp32 norm
// computed in-block; view-0 columns additionally scaled by 1/T.
// (round-0/1 known-good body, frozen)
__global__ __launch_bounds__(256) void k_prep(const float* __restrict__ f,
        const float* __restrict__ pts, _Float16* __restrict__ fh,
        unsigned char* __restrict__ valid, int* __restrict__ vcnt_part) {
  __shared__ unsigned tile[4][64 * 32];
  __shared__ float ssql[4][16][4];
  __shared__ float srn[64];
  int j0 = blockIdx.x * 64;
  int bn = blockIdx.y;
  int n = bn & 3;            // bn = b*N + n
  int tid = threadIdx.x;
  int jq = tid & 15;         // j-quad: j_local = 4*jq + {0..3}
  int dr = tid >> 4;         // 0..15: d-row group: d_local = 4*dr + {0..3}

  float ssq0 = 0.f, ssq1 = 0.f, ssq2 = 0.f, ssq3 = 0.f;
#pragma unroll
  for (int dt = 0; dt < 4; ++dt) {
    const float* fb = f + ((size_t)bn * D_ + dt * 64 + 4 * dr) * HW_ + j0 + 4 * jq;
    f32x4 r0 = *(const f32x4*)&fb[0];
    f32x4 r1 = *(const f32x4*)&fb[HW_];
    f32x4 r2 = *(const f32x4*)&fb[2 * HW_];
    f32x4 r3 = *(const f32x4*)&fb[3 * HW_];
    ssq0 = fmaf(r0[0], r0[0], fmaf(r1[0], r1[0], fmaf(r2[0], r2[0], fmaf(r3[0], r3[0], ssq0))));
    ssq1 = fmaf(r0[1], r0[1], fmaf(r1[1], r1[1], fmaf(r2[1], r2[1], fmaf(r3[1], r3[1], ssq1))));
    ssq2 = fmaf(r0[2], r0[2], fmaf(r1[2], r1[2], fmaf(r2[2], r2[2], fmaf(r3[2], r3[2], ssq2))));
    ssq3 = fmaf(r0[3], r0[3], fmaf(r1[3], r1[3], fmaf(r2[3], r2[3], fmaf(r3[3], r3[3], ssq3))));
    int p0 = 2 * dr;         // d-pair column within [0,32)
#pragma unroll
    for (int jj = 0; jj < 4; ++jj) {
      int jl = 4 * jq + jj;
      half2v h01, h23;
      h01[0] = (_Float16)r0[jj]; h01[1] = (_Float16)r1[jj];
      h23[0] = (_Float16)r2[jj]; h23[1] = (_Float16)r3[jj];
      tile[dt][jl * 32 + (p0 ^ (jl & 31))]       = __builtin_bit_cast(unsigned, h01);
      tile[dt][jl * 32 + ((p0 + 1) ^ (jl & 31))] = __builtin_bit_cast(unsigned, h23);
    }
  }
  // reduce sumsq over dr within wave (lanes jq, jq+16, jq+32, jq+48)
  ssq0 += __shfl_xor(ssq0, 16); ssq0 += __shfl_xor(ssq0, 32);
  ssq1 += __shfl_xor(ssq1, 16); ssq1 += __shfl_xor(ssq1, 32);
  ssq2 += __shfl_xor(ssq2, 16); ssq2 += __shfl_xor(ssq2, 32);
  ssq3 += __shfl_xor(ssq3, 16); ssq3 += __shfl_xor(ssq3, 32);
  if ((tid & 63) < 16) {
    int w = tid >> 6;
    ssql[w][jq][0] = ssq0; ssql[w][jq][1] = ssq1;
    ssql[w][jq][2] = ssq2; ssql[w][jq][3] = ssq3;
  }
  __syncthreads();
  if (tid < 64) {
    float s = ssql[0][tid >> 2][tid & 3] + ssql[1][tid >> 2][tid & 3]
            + ssql[2][tid >> 2][tid & 3] + ssql[3][tid >> 2][tid & 3];
    float r = 1.f / fmaxf(sqrtf(s), 1e-12f);
    srn[tid] = (n == 0) ? r * INV_T : r;
    size_t idx = (size_t)bn * HW_ + j0 + tid;
    const float* p = pts + idx * 3;
    float x = p[0], y = p[1], z = p[2];
    int v = (x * x + y * y + z * z) > 1e-12f ? 1 : 0;   // ||p|| > 1e-6
    valid[idx] = (unsigned char)v;
    unsigned long long mask = __ballot(v);
    if (tid == 0) vcnt_part[bn * NJB_ + blockIdx.x] = __popcll(mask);
  }
  __syncthreads();
  // readout: scale by srn[j], store 128 B contiguous per 32-lane group
  unsigned* outw = (unsigned*)fh;
  int c = tid & 31;
  int jr = tid >> 5;
#pragma unroll
  for (int dt = 0; dt < 4; ++dt) {
#pragma unroll
    for (int pass = 0; pass < 8; ++pass) {
      int j = jr + pass * 8;
      float sc = srn[j];
      unsigned u = tile[dt][j * 32 + (c ^ (j & 31))];
      half2v h = __builtin_bit_cast(half2v, u);
      half2v o;
      o[0] = (_Float16)((float)h[0] * sc);
      o[1] = (_Float16)((float)h[1] * sc);
      outw[((size_t)bn * HW_ + j0 + j) * (D_ / 2) + dt * 32 + c] =
          __builtin_bit_cast(unsigned, o);
    }
  }
}

// ---------------------------------------------------------------------------
// K2: NN search (exact ref semantics), standalone, vectorized scan (proven
// round 3). Also zeroes the merge ticket.
__global__ __launch_bounds__(256) void k_nn(const float* __restrict__ pts,
    const int* __restrict__ aidx, int* __restrict__ pos_idx,
    unsigned char* __restrict__ valid_a, int* __restrict__ ticket) {
  if (blockIdx.x == 0 && threadIdx.x == 0) *ticket = 0;
  int wave = threadIdx.x >> 6, lane = threadIdx.x & 63;
  int gid = blockIdx.x;
  int agrp = gid & 63;
  int b = (gid >> 6) & 7;
  int p = gid >> 9;
  int a = agrp * 4 + wave;
  int vv = p + 1;
  int col = aidx[(p * B_ + b) * A_ + a];
  const float* pi = pts + ((size_t)(b * N_) * HW_ + col) * 3;
  float ax = pi[0], ay = pi[1], az = pi[2];
  int vi = (ax * ax + ay * ay + az * az) > 1e-12f ? 1 : 0;
  const f32x4* pj4 = (const f32x4*)(pts + (size_t)(b * N_ + vv) * HW_ * 3);
  float best = INFINITY; int bidx = 0x7fffffff;
#pragma unroll 2
  for (int t = 0; t < HW_ / 256; ++t) {      // 12 iterations
    int jb = t * 256 + lane * 4;
    int base = t * 192 + lane * 3;           // float4 index: (jb*3)/4
    f32x4 q0 = pj4[base + 0];
    f32x4 q1 = pj4[base + 1];
    f32x4 q2 = pj4[base + 2];
    float px[4] = {q0[0], q0[3], q1[2], q2[1]};
    float py[4] = {q0[1], q1[0], q1[3], q2[2]};
    float pz[4] = {q0[2], q1[1], q2[0], q2[3]};
#pragma unroll
    for (int k = 0; k < 4; ++k) {
      float x = px[k], y = py[k], z = pz[k];
      int vj = (x * x + y * y + z * z) > 1e-12f;
      float dx = ax - x, dy = ay - y, dz = az - z;
      float dist = sqrtf(dx * dx + dy * dy + dz * dz);
      int j = jb + k;
      if (vj && (dist < best || (dist == best && j < bidx))) { best = dist; bidx = j; }
    }
  }
#pragma unroll
  for (int o = 32; o > 0; o >>= 1) {
    float ob = __shfl_xor(best, o);
    int oi = __shfl_xor(bidx, o);
    if (ob < best || (ob == best && oi < bidx)) { best = ob; bidx = oi; }
  }
  if (lane == 0) {
    int ai = (p * B_ + b) * A_ + a;
    pos_idx[ai] = (bidx == 0x7fffffff) ? 0 : bidx;
    valid_a[ai] = (best < 0.1f) && vi;
  }
}

// ---------------------------------------------------------------------------
// K3: MFMA f16 GEMM, 128x128 tile, 4 waves (2x2 of 64x64), BK=64, dbuf LDS.
// K-loop/staging identical to round-5 (proven). ROUND-6: epilogue rewritten —
// the old one did 128 serially-chained __shfl_xor (ds_swizzle) ops per wave
// (16 (m,reg) iters x two 4-deep reduction trees); theory E says those latency
// chains are the 60-us invariant. New epilogue: after the K-loop the 64 KB
// As/Bs LDS is dead -> reuse as [64 j][132] f32 scratch (+4 pad = 2-way-free
// banks). Two passes (one per 64-j half = existing partials granularity):
// owning waves dump acc via f32x4 stores; each of 256 threads then owns
// (anchor, 32-j half) and reduces sequentially in registers — no cross-lane
// ops except one final shfl_xor(1) pair-merge. Same exp/fmax counts, same
// partials/possim semantics (summation order differs; fp-benign).
#define STAGE_AB(KK, BUF) do {                                                 \
  _Pragma("unroll")                                                            \
  for (int cc = 0; cc < 4; ++cc) {                                             \
    const _Float16* srcA = fA + (size_t)colA[cc] * D_ + (KK) * 64 + gsw * 8;   \
    __builtin_amdgcn_global_load_lds(                                          \
        (const __attribute__((address_space(1))) void*)srcA,                   \
        (__attribute__((address_space(3))) void*)&As[BUF][(wid * 32 + cc * 8) * LDKH], \
        16, 0, 0);                                                             \
  }                                                                            \
  _Pragma("unroll")                                                            \
  for (int cc = 0; cc < 4; ++cc) {                                             \
    const _Float16* srcB = fB + (size_t)rowB[cc] * D_ + (KK) * 64 + gsw * 8;   \
    __builtin_amdgcn_global_load_lds(                                          \
        (const __attribute__((address_space(1))) void*)srcB,                   \
        (__attribute__((address_space(3))) void*)&Bs[BUF][(wid * 32 + cc * 8) * LDKH], \
        16, 0, 0);                                                             \
  }                                                                            \
} while (0)

__global__ __launch_bounds__(256) void k_gemm(const _Float16* __restrict__ fh,
    const int* __restrict__ aidx, const unsigned char* __restrict__ valid,
    const int* __restrict__ pos_idx, float* __restrict__ possim,
    float2* __restrict__ partials) {
  __shared__ __align__(16) char smem[65536];
  _Float16 (*As)[128 * LDKH] = reinterpret_cast<_Float16 (*)[128 * LDKH]>(smem);
  _Float16 (*Bs)[128 * LDKH] = reinterpret_cast<_Float16 (*)[128 * LDKH]>(smem + 32768);
  float (*scr)[132] = reinterpret_cast<float (*)[132]>(smem);   // reused post-K-loop

  int jt = blockIdx.x;
  int pbm = blockIdx.y;          // 0..47: pb*2 + mt
  int pb = pbm >> 1, mt = pbm & 1;
  int b = pb & 7, p = pb >> 3, v = p + 1;
  int tid = threadIdx.x;
  int wid = tid >> 6, lane = tid & 63;   // 4 waves
  int wr = wid >> 1, wc = wid & 1;       // 2x2 of 64x64
  int j0 = jt * 128;
  const _Float16* fA = fh + (size_t)(b * N_) * HW_ * D_;        // view 0
  const _Float16* fB = fh + (size_t)(b * N_ + v) * HW_ * D_;    // view v

  // staging: lane -> (row offset rl = lane>>3, granule gl = lane&7),
  // source granule pre-swizzled: gsw = gl ^ rl = g ^ (row&7).
  int rl = lane >> 3;
  int gl = lane & 7;
  int gsw = gl ^ rl;
  int colA[4];
#pragma unroll
  for (int c = 0; c < 4; ++c)
    colA[c] = aidx[(p * B_ + b) * A_ + mt * 128 + wid * 32 + c * 8 + rl];
  int rowB[4];
#pragma unroll
  for (int c = 0; c < 4; ++c) rowB[c] = j0 + wid * 32 + c * 8 + rl;

  f32x4 acc[4][4];
#pragma unroll
  for (int m = 0; m < 4; ++m)
#pragma unroll
    for (int n = 0; n < 4; ++n) acc[m][n] = (f32x4)0.f;

  int kg = lane >> 4;        // k-granule 0..3
  int fr = lane & 15;        // fragment row

  STAGE_AB(0, 0);
  __syncthreads();           // drains vmcnt(0): buf0 ready

#pragma unroll
  for (int kk = 0; kk < 4; ++kk) {
    const int cur = kk & 1;
    if (kk < 3) STAGE_AB(kk + 1, cur ^ 1);   // issue-early: hides under MFMA
#pragma unroll
    for (int s = 0; s < 2; ++s) {
      half8 af[4], bf[4];
      int G = s * 4 + kg;
#pragma unroll
      for (int m = 0; m < 4; ++m) {
        int row = wr * 64 + m * 16 + fr;
        af[m] = *(half8*)&As[cur][row * LDKH + ((G ^ (row & 7)) << 3)];
      }
#pragma unroll
      for (int n = 0; n < 4; ++n) {
        int row = wc * 64 + n * 16 + fr;
        bf[n] = *(half8*)&Bs[cur][row * LDKH + ((G ^ (row & 7)) << 3)];
      }
      __builtin_amdgcn_s_setprio(1);
#pragma unroll
      for (int m = 0; m < 4; ++m)
#pragma unroll
        for (int n = 0; n < 4; ++n)
          acc[m][n] = __builtin_amdgcn_mfma_f32_16x16x32_f16(af[m], bf[n], acc[m][n], 0, 0, 0);
      __builtin_amdgcn_s_setprio(0);
    }
    if (kk < 3) __syncthreads();   // drains prefetch vmcnt; next buf ready
  }

  // ---- epilogue (LDS-transpose, sequential per-thread reduction) ----
  __syncthreads();   // all As/Bs reads retired -> LDS reusable as scratch

  int vrow = b * N_ + v;
  int a_loc = tid >> 1, h = tid & 1;          // anchor 0..127, j-half 0/1
  int aig = pb * A_ + mt * 128 + a_loc;
  int pidx = pos_idx[aig];

#pragma unroll
  for (int pss = 0; pss < 2; ++pss) {
    if (wc == pss) {
      // dump this wave's 64x64 acc tile: value (m,n,reg) is anchor
      // wr*64+m*16+kg*4+reg, local column n*16+fr within the pss 64-j half
#pragma unroll
      for (int m = 0; m < 4; ++m)
#pragma unroll
        for (int n = 0; n < 4; ++n)
          *(f32x4*)&scr[n * 16 + fr][wr * 64 + m * 16 + kg * 4] = acc[m][n];
    }
    __syncthreads();
    int jbase = j0 + pss * 64 + h * 32;
    const unsigned* vp = (const unsigned*)(valid + (size_t)vrow * HW_ + jbase);
    unsigned vw[8];
#pragma unroll
    for (int w = 0; w < 8; ++w) vw[w] = vp[w];
    float vv[32];
#pragma unroll
    for (int jj = 0; jj < 32; ++jj) vv[jj] = scr[h * 32 + jj][a_loc];
    float mx = -INFINITY;
#pragma unroll
    for (int jj = 0; jj < 32; ++jj) {
      if ((vw[jj >> 2] >> ((jj & 3) * 8)) & 0xff) mx = fmaxf(mx, vv[jj]);
      if (jbase + jj == pidx) possim[aig] = vv[jj];
    }
    float S = 0.f;
#pragma unroll
    for (int jj = 0; jj < 32; ++jj) {
      if ((vw[jj >> 2] >> ((jj & 3) * 8)) & 0xff) S += __expf(vv[jj] - mx);
    }
    // merge the two 32-j halves of this anchor (partner thread = tid^1)
    float am = fmaxf(mx, __shfl_xor(mx, 1));
    float Ss = (mx == am) ? S : S * __expf(mx - am);
    Ss += __shfl_xor(Ss, 1);
    if (h == 0) partials[(size_t)aig * NJT2_ + (jt * 2 + pss)] = make_float2(am, Ss);
    __syncthreads();   // pass-1 reads done before pass-2 overwrites scratch
  }
}

// ---------------------------------------------------------------------------
// K4: merge partial LSEs (4 threads/anchor), per-(pair,batch) reduction +
// include; last block (device ticket) computes the final scalar.
__global__ __launch_bounds__(1024) void k_merge(const float2* __restrict__ partials,
    const float* __restrict__ possim, const unsigned char* __restrict__ valid_a,
    const int* __restrict__ vcnt_part, float* __restrict__ lossb,
    int* __restrict__ incb, int* __restrict__ ticket, float* __restrict__ out) {
  int pb = blockIdx.x;
  int b = pb & 7, p = pb >> 3;
  int tid = threadIdx.x;
  int a = tid >> 2, q = tid & 3;
  int ai = pb * A_ + a;

  __shared__ float ss[16]; __shared__ int sc[16];
  __shared__ int v0c, vvc;
  if (tid == 0) { v0c = 0; vvc = 0; }
  __syncthreads();
  if (tid < NJB_) atomicAdd(&v0c, vcnt_part[(b * N_ + 0) * NJB_ + tid]);
  else if (tid < 2 * NJB_) atomicAdd(&vvc, vcnt_part[(b * N_ + p + 1) * NJB_ + (tid - NJB_)]);

  // each thread: 12 (m,S) pairs = 6 float4, contiguous 96 B
  const float4* pt = (const float4*)partials + (size_t)ai * 24 + q * 6;
  float4 vv4[6];
#pragma unroll
  for (int i = 0; i < 6; ++i) vv4[i] = pt[i];
  float mx = -INFINITY;
#pragma unroll
  for (int i = 0; i < 6; ++i) { mx = fmaxf(mx, vv4[i].x); mx = fmaxf(mx, vv4[i].z); }
  float S = 0.f;
  if (mx != -INFINITY) {
#pragma unroll
    for (int i = 0; i < 6; ++i) {
      S += vv4[i].y * __expf(vv4[i].x - mx);
      S += vv4[i].w * __expf(vv4[i].z - mx);
    }
  }
  // merge across the 4 lanes of this anchor
  float am = mx;
#pragma unroll
  for (int o = 1; o < 4; o <<= 1) am = fmaxf(am, __shfl_xor(am, o));
  float Sg = S * ((mx == am) ? 1.f : __expf(mx - am));
#pragma unroll
  for (int o = 1; o < 4; o <<= 1) Sg += __shfl_xor(Sg, o);

  float contrib = 0.f; int cnt = 0;
  if (q == 0) {
    float lse = (am == -INFINITY) ? -INFINITY : am + logf(Sg);
    if (valid_a[ai]) { contrib = lse - possim[ai]; cnt = 1; }
  }
  // wave reduce (leads are lanes with (lane&3)==0)
#pragma unroll
  for (int o = 4; o < 64; o <<= 1) {
    contrib += __shfl_xor(contrib, o);
    cnt += __shfl_xor(cnt, o);
  }
  if ((tid & 63) == 0) { ss[tid >> 6] = contrib; sc[tid >> 6] = cnt; }
  __syncthreads();
  if (tid == 0) {
    float s = 0.f; int c = 0;
#pragma unroll
    for (int i = 0; i < 16; ++i) { s += ss[i]; c += sc[i]; }
    float lb = s / (float)(c > 1 ? c : 1);
    int inc = (c >= 5) && (v0c >= 10) && (vvc >= 10);
    lossb[pb] = lb;
    incb[pb] = inc;
    __threadfence();
    int old = atomicAdd(ticket, 1);
    if (old == NP_ * B_ - 1) {
      __threadfence();
      float total = 0.f;
      for (int pp = 0; pp < NP_; ++pp) {
        float sacc = 0.f; int n = 0;
        for (int bb = 0; bb < B_; ++bb)
          if (incb[pp * B_ + bb]) { sacc += lossb[pp * B_ + bb]; ++n; }
        total += (n > 0) ? sacc / (float)n : 0.f;
      }
      out[0] = total / (float)NP_;
    }
  }
}

// ---------------------------------------------------------------------------
extern "C" void kernel_launch(void* const* d_in, const int* in_sizes, int n_in,
                              void* d_out, int out_size, void* d_ws, size_t ws_size,
                              hipStream_t stream) {
  const float* f   = (const float*)d_in[0];   // [B,N,D,H,W] fp32
  const float* pts = (const float*)d_in[1];   // [B,N,H,W,3] fp32
  const int* aidx  = (const int*)d_in[2];     // [NP,B,A] int32
  float* out = (float*)d_out;

  char* ws = (char*)d_ws;
  _Float16* fh          = (_Float16*)(ws);                    // 32*3072*256*2 = 50,331,648
  unsigned char* valid  = (unsigned char*)(ws + 50331648);    // 98,304
  int* pos_idx          = (int*)(ws + 50429952);              // 24,576
  unsigned char* valid_a= (unsigned char*)(ws + 50454528);    // 6,144
  float* possim         = (float*)(ws + 50460672);            // 24,576
  float* lossb          = (float*)(ws + 50485248);            // 96 (pad to 128)
  int* incb             = (int*)(ws + 50485376);              // 96 (pad to 128)
  float2* partials      = (float2*)(ws + 50485504);           // 6144*48*8 = 2,359,296
  int* vcnt_part        = (int*)(ws + 52844800);              // 32*48*4 = 6,144
  int* ticket           = (int*)(ws + 52850944);              // 4
  // total ws usage: 52,850,948 bytes

  k_prep<<<dim3(HW_ / 64, B_ * N_), 256, 0, stream>>>(f, pts, fh, valid, vcnt_part);
  k_nn<<<NP_ * B_ * (A_ / 4), 256, 0, stream>>>(pts, aidx, pos_idx, valid_a, ticket);
  k_gemm<<<dim3(24, NP_ * B_ * 2), 256, 0, stream>>>(fh, aidx, valid, pos_idx, possim, partials);
  k_merge<<<NP_ * B_, 1024, 0, stream>>>(partials, possim, valid_a, vcnt_part, lossb, incb, ticket, out);
}